// Round 9
// baseline (292.914 us; speedup 1.0000x reference)
//
#include <hip/hip_runtime.h>
#include <math.h>

#define NIMG 8
#define TT   159882
#define KTOT 4507
#define POST 1000
#define NSUB 32

__constant__ int c_n[5]   = {120000,30000,7500,1875,507};
__constant__ int c_off[5] = {0,120000,150000,157500,159375};
__constant__ int c_k[5]   = {1000,1000,1000,1000,507};
__constant__ int c_pos[5] = {0,1000,2000,3000,4000};

__device__ __forceinline__ unsigned fkey(float f){
  unsigned u=__float_as_uint(f);
  return (u&0x80000000u)? ~u : (u|0x80000000u);
}

// ---------------- K0: zero global histograms + rank array ---------------------
__global__ __launch_bounds__(256) void k_zero(unsigned* __restrict__ ghist,
                                              int* __restrict__ grank){
  int i=blockIdx.x*256+threadIdx.x;
  if(i<40*2048) ghist[i]=0u;
  int j=i-40*2048;
  if(j>=0 && j<NIMG*KTOT) grank[j]=0;
}

// ---------------- K1a: distributed radix histogram (one round) ----------------
template<int RND>
__global__ __launch_bounds__(256) void k_hist(const float* __restrict__ obj,
    const unsigned* __restrict__ gpref, unsigned* __restrict__ ghist){
  constexpr int sh=(RND==0)?21:(RND==1)?10:0;
  constexpr int nb=(RND==2)?1024:2048;
  constexpr unsigned msk=(unsigned)(nb-1);
  const int il=blockIdx.x, sub=blockIdx.y;
  const int img=il/5, lvl=il%5;
  const int n=c_n[lvl], k=c_k[lvl];
  if(k>=n) return;
  const int chunk=(n+NSUB-1)/NSUB;
  const int start=sub*chunk, end=min(start+chunk,n);
  if(start>=end) return;
  const float* o=obj+(size_t)img*TT+c_off[lvl];
  __shared__ unsigned hist[2048];
  const unsigned prefix=(RND==0)?0u:gpref[il];
  for(int i=threadIdx.x;i<nb;i+=256) hist[i]=0u;
  __syncthreads();
  for(int i=start+threadIdx.x;i<end;i+=256){
    unsigned key=fkey(o[i]);
    if(RND==0){
      atomicAdd(&hist[(key>>sh)&msk],1u);
    } else {
      constexpr unsigned hiMask=0xFFFFFFFFu<<((RND==1)?21:10);
      if((key&hiMask)==prefix) atomicAdd(&hist[(key>>sh)&msk],1u);
    }
  }
  __syncthreads();
  for(int b=threadIdx.x;b<nb;b+=256){
    unsigned v=hist[b];
    if(v) atomicAdd(&ghist[il*2048+b],v);
  }
}

// ---------------- K1b: pick bucket via register suffix-sum + LDS tree ---------
template<int RND>
__global__ __launch_bounds__(256) void k_scan(unsigned* __restrict__ ghist,
    unsigned* __restrict__ gpref, int* __restrict__ gkrem,
    int* __restrict__ gcnt){
  constexpr int sh=(RND==0)?21:(RND==1)?10:0;
  constexpr int nb=(RND==2)?1024:2048;
  constexpr int C=nb/256;
  const int il=blockIdx.x, lvl=il%5;
  const int n=c_n[lvl], k=c_k[lvl];
  const int t=threadIdx.x;
  __shared__ unsigned tot[256];
  if(k>=n){
    if(RND==2 && t==0){ gpref[il]=0u; gkrem[il]=0; gcnt[il*2]=0; gcnt[il*2+1]=0; }
    return;
  }
  const int kr=(RND==0)?k:gkrem[il];
  unsigned v[C];
#pragma unroll
  for(int i=0;i<C;i++) v[i]=ghist[il*2048+t*C+i];
#pragma unroll
  for(int i=C-2;i>=0;i--) v[i]+=v[i+1];          // local suffix sum (registers)
  tot[t]=v[0];
  __syncthreads();
#pragma unroll
  for(int d=1;d<256;d<<=1){                       // inclusive suffix scan of totals
    unsigned add=(t+d<256)?tot[t+d]:0u;
    __syncthreads();
    tot[t]+=add;
    __syncthreads();
  }
  unsigned tail=(t<255)?tot[t+1]:0u;
#pragma unroll
  for(int i=0;i<C;i++){
    unsigned suf=v[i]+tail;
    unsigned sufn=((i<C-1)?v[i+1]:0u)+tail;
    if(suf>=(unsigned)kr && sufn<(unsigned)kr){
      unsigned prevPref=(RND==0)?0u:gpref[il];
      gpref[il]=prevPref|((unsigned)(t*C+i)<<sh);
      gkrem[il]=kr-(int)sufn;
    }
  }
  for(int b=t;b<2048;b+=256) ghist[il*2048+b]=0u; // ready for next round/replay
  if(RND==2 && t==0){ gcnt[il*2]=0; gcnt[il*2+1]=0; }
}

// ---------------- K1c: distributed selection against final threshold ---------
__global__ __launch_bounds__(256) void k_sel(const float* __restrict__ obj,
    const unsigned* __restrict__ gpref, const int* __restrict__ gkrem,
    int* __restrict__ gcnt, int* __restrict__ sel, int* __restrict__ eqbuf){
  const int il=blockIdx.x, sub=blockIdx.y;
  const int img=il/5, lvl=il%5;
  const int n=c_n[lvl], k=c_k[lvl];
  const int chunk=(n+NSUB-1)/NSUB;
  const int start=sub*chunk, end=min(start+chunk,n);
  if(start>=end) return;
  int* s=sel+img*KTOT+c_pos[lvl];
  if(k>=n){
    for(int i=start+threadIdx.x;i<end;i+=256) s[i]=i;
    return;
  }
  const float* o=obj+(size_t)img*TT+c_off[lvl];
  const unsigned t=gpref[il];
  const int krem=gkrem[il];
  for(int i=start+threadIdx.x;i<end;i+=256){
    unsigned key=fkey(o[i]);
    if(key>t){ s[atomicAdd(&gcnt[il*2],1)]=i; }
    else if(key==t && krem>0){ int p=atomicAdd(&gcnt[il*2+1],1); if(p<2048) eqbuf[il*2048+p]=i; }
  }
}

// ---------------- K1d: eq-tiebreak picks + level rank sort --------------------
__global__ __launch_bounds__(256) void k_sort(const float* __restrict__ obj,
    const int* __restrict__ gkrem, const int* __restrict__ gcnt,
    int* __restrict__ sel, int* __restrict__ eqbuf){
  const int il=blockIdx.x, img=il/5, lvl=il%5;
  const int n=c_n[lvl], k=c_k[lvl];
  const float* o=obj+(size_t)img*TT+c_off[lvl];
  int* s=sel+img*KTOT+c_pos[lvl];
  __shared__ unsigned long long skey[1024];
  if(k<n){
    const int krem=gkrem[il];
    if(krem>0 && threadIdx.x==0){
      int cgt=gcnt[il*2];
      int ceq=min(gcnt[il*2+1],2048);
      int* eq=eqbuf+il*2048;
      for(int r2=0;r2<krem;r2++){
        int mn=0x7fffffff,mi=0;
        for(int j=0;j<ceq;j++) if(eq[j]<mn){mn=eq[j];mi=j;}
        s[cgt+r2]=mn; eq[mi]=0x7fffffff;
      }
    }
    __syncthreads();
  }
  for(int i=threadIdx.x;i<k;i+=256){
    int idx=s[i];
    skey[i]=((unsigned long long)fkey(o[idx])<<32)|(unsigned)(~(unsigned)idx);
  }
  __syncthreads();
  for(int i=threadIdx.x;i<k;i+=256){
    unsigned long long mk=skey[i];
    int rank=0;
    for(int j=0;j<k;j++) rank+=(skey[j]>mk)?1:0;
    int idx=(int)(~(unsigned)(mk&0xFFFFFFFFu));
    s[rank]=idx+c_off[lvl];
  }
}

// ---------------- K2a: decode+clip+score, build global sort keys, image max ----
__global__ __launch_bounds__(256) void k_decode(const float* __restrict__ obj,
    const float* __restrict__ del, const float* __restrict__ anc,
    const int* __restrict__ sel, float* __restrict__ pbox, float* __restrict__ pscore,
    int* __restrict__ plvl, unsigned long long* __restrict__ gkey,
    float* __restrict__ gmax){
  const int img=blockIdx.x;
  __shared__ float smax[256];
  const float BCLIP=(float)4.135166556742356;  // log(1000/16)
  float lm=0.f;
  for(int pos=threadIdx.x;pos<KTOT;pos+=256){
    int lvl = pos<1000?0:pos<2000?1:pos<3000?2:pos<4000?3:4;
    int tdx = sel[img*KTOT+pos];
    float logit = obj[(size_t)img*TT+tdx];
    const float* a=anc+4*(size_t)tdx;
    const float* d=del+((size_t)img*TT+tdx)*4;
    float w=a[2]-a[0], h=a[3]-a[1];
    float cx=a[0]+0.5f*w, cy=a[1]+0.5f*h;
    float dw=fminf(d[2],BCLIP), dh=fminf(d[3],BCLIP);
    float pcx=d[0]*w+cx, pcy=d[1]*h+cy;
    float pw=expf(dw)*w, ph=expf(dh)*h;
    float x1=pcx-0.5f*pw, y1=pcy-0.5f*ph;
    float x2=pcx+0.5f*pw, y2=pcy+0.5f*ph;
    x1=fminf(fmaxf(x1,0.f),800.f); y1=fminf(fmaxf(y1,0.f),800.f);
    x2=fminf(fmaxf(x2,0.f),800.f); y2=fminf(fmaxf(y2,0.f),800.f);
    int valid=(x2-x1>=1e-3f)&&(y2-y1>=1e-3f);
    float sc=1.f/(1.f+expf(-logit));
    float sv=valid? sc : -INFINITY;
    gkey[img*KTOT+pos]=((unsigned long long)fkey(sv)<<32)|(unsigned)(KTOT-1-pos);
    float* pb=pbox+((size_t)img*KTOT+pos)*4;
    pb[0]=x1; pb[1]=y1; pb[2]=x2; pb[3]=y2;
    pscore[img*KTOT+pos]=sc;
    plvl[img*KTOT+pos]=lvl|(valid?0:256);
    lm=fmaxf(lm,fmaxf(fmaxf(x1,y1),fmaxf(x2,y2)));
  }
  smax[threadIdx.x]=lm; __syncthreads();
  for(int st=128;st>0;st>>=1){
    if(threadIdx.x<st) smax[threadIdx.x]=fmaxf(smax[threadIdx.x],smax[threadIdx.x+st]);
    __syncthreads();
  }
  if(threadIdx.x==0) gmax[img]=smax[0];
}

// ---------------- K2b: partial rank counts, 256x256 tiles ---------------------
__global__ __launch_bounds__(256) void k_rankp(const unsigned long long* __restrict__ gkey,
    int* __restrict__ grank){
  const int img=blockIdx.x, ic=blockIdx.y, jc=blockIdx.z;
  __shared__ unsigned long long sk[256];
  const int jbase=jc*256;
  const int jend=min(256, KTOT-jbase);
  const int i=ic*256+threadIdx.x;
  if(threadIdx.x<jend) sk[threadIdx.x]=gkey[img*KTOT+jbase+threadIdx.x];
  __syncthreads();
  if(i>=KTOT) return;
  const unsigned long long mk=gkey[img*KTOT+i];
  int r=0;
  #pragma unroll 4
  for(int j=0;j<jend;j++) r+=(sk[j]>mk)?1:0;
  if(r) atomicAdd(&grank[img*KTOT+i], r);
}

// ---------------- K2c: scatter by rank ---------------------------------------
__global__ __launch_bounds__(256) void k_scatter(const int* __restrict__ grank,
    const float4* __restrict__ pbox, const float* __restrict__ pscore,
    const int* __restrict__ plvl,
    float4* __restrict__ sbox, float* __restrict__ sscore,
    int* __restrict__ slvl, int* __restrict__ ssupp){
  const int img=blockIdx.x/18, chunk=blockIdx.x%18;
  const int pos=chunk*256+threadIdx.x;
  if(pos>=KTOT) return;
  const int rank=grank[img*KTOT+pos];
  sbox[(size_t)img*KTOT+rank]=pbox[(size_t)img*KTOT+pos];
  sscore[img*KTOT+rank]=pscore[img*KTOT+pos];
  int lv=plvl[img*KTOT+pos];
  slvl[img*KTOT+rank]=lv&0xFF;
  ssupp[img*KTOT+rank]=(lv>>8)&1;   // invalid -> pre-suppressed
}

// ---------------- K3a: candidate list; LDS-staged predicate, wave-0 ballot ----
__global__ __launch_bounds__(256) void k_list(const float* __restrict__ sbox,
    const int* __restrict__ slvl, const int* __restrict__ ssupp,
    const float* __restrict__ gmax,
    int* __restrict__ lists, int* __restrict__ mcnt,
    float4* __restrict__ nbox, float* __restrict__ narea){
  const int img=blockIdx.x/5, lvl=blockIdx.x%5;
  const int tid=threadIdx.x;
  __shared__ unsigned char s_ok[KTOT];
  __shared__ int s_list[1024];
  __shared__ int s_m;
  for(int i=tid;i<KTOT;i+=256)
    s_ok[i]=(slvl[img*KTOT+i]==lvl && ssupp[img*KTOT+i]==0)?1:0;
  __syncthreads();
  if(tid<64){
    int base=0;
    for(int t=0;t<KTOT;t+=64){
      int r=t+tid;
      bool pred=(r<KTOT) && s_ok[r];
      unsigned long long b=__ballot(pred);
      int pre=__popcll(b & ((1ull<<tid)-1ull));
      if(pred) s_list[base+pre]=r;
      base+=__popcll(b);
    }
    if(tid==0){ s_m=base; mcnt[blockIdx.x]=base; }
  }
  __syncthreads();
  const int m=s_m;
  const float off=(float)lvl*(gmax[img]+1.0f);   // replicate ref offset math exactly
  const float4* sb4=(const float4*)sbox;
  for(int i=tid;i<m;i+=256){
    int r=s_list[i];
    lists[blockIdx.x*1024+i]=r;
    float4 bx=sb4[(size_t)img*KTOT+r];
    float a0=bx.x+off, a1=bx.y+off, a2=bx.z+off, a3=bx.w+off;
    nbox[blockIdx.x*1024+i]=make_float4(a0,a1,a2,a3);
    narea[blockIdx.x*1024+i]=(a2-a0)*(a3-a1);
  }
}

// ---------------- K3b: pairwise suppression bitmasks, 1 word/thread ------------
__global__ __launch_bounds__(256) void k_mask(const float4* __restrict__ nbox,
    const float* __restrict__ narea, const int* __restrict__ mcnt,
    unsigned long long* __restrict__ mask){
  const int il=blockIdx.x;
  const int rc=blockIdx.y>>4, w=blockIdx.y&15;
  const int m=mcnt[il];
  const int r0=rc*256;
  if(r0>=m) return;
  const int i=r0+threadIdx.x;
  const int wlast=(m+63)>>6;
  __shared__ float4 sb[64];
  __shared__ float  sa[64];
  unsigned long long bits=0ull;
  const bool block_active = (w>=rc*4) && (w<wlast);   // rc*4 == min wi in block
  if(block_active){
    const int jend=min(64, m-w*64);
    if(threadIdx.x<64 && threadIdx.x<jend){
      sb[threadIdx.x]=nbox[il*1024+w*64+threadIdx.x];
      sa[threadIdx.x]=narea[il*1024+w*64+threadIdx.x];
    }
    __syncthreads();
    const int wi=i>>6;
    if(i<m && w>=wi){
      const float4 bi=nbox[il*1024+i];
      const float  ai=narea[il*1024+i];
      for(int jj=0;jj<jend;++jj){
        const float4 bj=sb[jj];                 // LDS broadcast
        float ltx=fmaxf(bi.x,bj.x), lty=fmaxf(bi.y,bj.y);
        float rbx=fminf(bi.z,bj.z), rby=fminf(bi.w,bj.w);
        float wx=fmaxf(rbx-ltx,0.f), wy=fmaxf(rby-lty,0.f);
        float inter=wx*wy;
        float iou=inter/((ai+sa[jj])-inter);
        bits |= (iou>0.7f)? (1ull<<jj) : 0ull;
      }
      if(w==wi){ int b=i&63; bits &= ~((2ull<<b)-1ull); }  // keep only j>i
    }
  }
  if(i<m) mask[((size_t)il*1024+i)*16+w]=bits;
}

// ---------------- K3c: greedy reduce; 16-wide groups, branch-free updates -----
__global__ __launch_bounds__(256) void k_reduce(const unsigned long long* __restrict__ mask,
    const int* __restrict__ mcnt, const int* __restrict__ lists,
    int* __restrict__ ssupp){
  const int il=blockIdx.x, img=il/5;
  const int m=mcnt[il];
  __shared__ unsigned long long smask[1024*16];   // 128 KB slab
  // cooperative global->LDS copy, 8 loads in flight per thread, no tail loop
  {
    const float4* g4=(const float4*)(mask + (size_t)il*1024*16);
    float4* l4=(float4*)smask;
    const int tot4=(m*8+2047)&~2047;              // <= 8192 always (m<=1000)
    for(int i=threadIdx.x;i<tot4;i+=2048){
      float4 r0=g4[i      ], r1=g4[i+ 256], r2=g4[i+ 512], r3=g4[i+ 768];
      float4 r4=g4[i+1024], r5=g4[i+1280], r6=g4[i+1536], r7=g4[i+1792];
      l4[i      ]=r0; l4[i+ 256]=r1; l4[i+ 512]=r2; l4[i+ 768]=r3;
      l4[i+1024]=r4; l4[i+1280]=r5; l4[i+1536]=r6; l4[i+1792]=r7;
    }
  }
  __syncthreads();
  if(threadIdx.x>=64) return;
  const int lane=threadIdx.x;
  const bool ld = lane<16;
  unsigned long long remv=0ull;
  unsigned long long c0,c1,c2,c3,c4,c5,c6,c7,c8,c9,c10,c11,c12,c13,c14,c15;
  unsigned long long n0,n1,n2,n3,n4,n5,n6,n7,n8,n9,n10,n11,n12,n13,n14,n15;
#define LD(r,b) ((ld && ((b)+(r))<m) ? smask[(unsigned)((b)+(r))*16+lane] : 0ull)
  c0 =LD(0,0);  c1 =LD(1,0);  c2 =LD(2,0);  c3 =LD(3,0);
  c4 =LD(4,0);  c5 =LD(5,0);  c6 =LD(6,0);  c7 =LD(7,0);
  c8 =LD(8,0);  c9 =LD(9,0);  c10=LD(10,0); c11=LD(11,0);
  c12=LD(12,0); c13=LD(13,0); c14=LD(14,0); c15=LD(15,0);
  for(int g=0;;++g){
    const int nb=(g+1)*16;
    n0 =LD(0,nb);  n1 =LD(1,nb);  n2 =LD(2,nb);  n3 =LD(3,nb);
    n4 =LD(4,nb);  n5 =LD(5,nb);  n6 =LD(6,nb);  n7 =LD(7,nb);
    n8 =LD(8,nb);  n9 =LD(9,nb);  n10=LD(10,nb); n11=LD(11,nb);
    n12=LD(12,nb); n13=LD(13,nb); n14=LD(14,nb); n15=LD(15,nb);
    // lane-local simulated decisions for this group of 16 (base%64 in {0,16,32,48})
    const int base=g*16;
    const int w=base>>6;          // wave-uniform
    const int bb=base&63;
    unsigned t8=(unsigned)(remv>>bb);
    unsigned am=0u;
#define DEC(r,cr) { unsigned alive=1u^((t8>>(r))&1u); am|=alive<<(r); \
                    if(alive) t8|=(unsigned)((cr)>>bb); }
    DEC(0,c0)  DEC(1,c1)  DEC(2,c2)  DEC(3,c3)
    DEC(4,c4)  DEC(5,c5)  DEC(6,c6)  DEC(7,c7)
    DEC(8,c8)  DEC(9,c9)  DEC(10,c10) DEC(11,c11)
    DEC(12,c12) DEC(13,c13) DEC(14,c14) DEC(15,c15)
#undef DEC
    const int rem=m-base;
    unsigned vm=(rem>=16)?0xffffu:((rem<=0)?0u:((1u<<rem)-1u));
    am&=vm;
    unsigned am_w=__builtin_amdgcn_readlane(am, w);   // SALU path, no LDS op
#define APP(r,cr) { unsigned long long mk64=0ull-(unsigned long long)((am_w>>(r))&1u); \
                    remv|=(cr)&mk64; }
    APP(0,c0)  APP(1,c1)  APP(2,c2)  APP(3,c3)
    APP(4,c4)  APP(5,c5)  APP(6,c6)  APP(7,c7)
    APP(8,c8)  APP(9,c9)  APP(10,c10) APP(11,c11)
    APP(12,c12) APP(13,c13) APP(14,c14) APP(15,c15)
#undef APP
    if(nb>=m) break;
    c0 =n0;  c1 =n1;  c2 =n2;  c3 =n3;  c4 =n4;  c5 =n5;  c6 =n6;  c7 =n7;
    c8 =n8;  c9 =n9;  c10=n10; c11=n11; c12=n12; c13=n13; c14=n14; c15=n15;
  }
#undef LD
  const int* list = lists + il*1024;
  for(int t=0;t<m;t+=64){
    int i=t+lane;
    unsigned long long word=__shfl(remv, (i<m? i:0)>>6);
    if(i<m && ((word>>(i&63))&1ull)) ssupp[img*KTOT+list[i]]=1;
  }
}

// ---------------- K4: compact survivors; LDS-staged predicate -----------------
__global__ __launch_bounds__(256) void k_out(const float* __restrict__ sbox,
    const float* __restrict__ sscore, const int* __restrict__ ssupp,
    float* __restrict__ out){
  const int img=blockIdx.x;
  const int tid=threadIdx.x;
  __shared__ unsigned char s_ok[KTOT];
  __shared__ unsigned short list[POST];
  __shared__ int s_c;
  for(int i=tid;i<KTOT;i+=256) s_ok[i]=(ssupp[img*KTOT+i]==0)?1:0;
  __syncthreads();
  if(tid<64){
    int base=0;
    for(int t=0;t<KTOT && base<POST;t+=64){
      int r=t+tid;
      bool pred=(r<KTOT) && s_ok[r];
      unsigned long long b=__ballot(pred);
      int pre=__popcll(b & ((1ull<<tid)-1ull));
      if(pred && base+pre<POST) list[base+pre]=(unsigned short)r;
      base+=__popcll(b);
    }
    if(tid==0) s_c=min(base,POST);
  }
  __syncthreads();
  const int c=s_c;
  for(int o=tid;o<POST;o+=256){
    float* row=out+((size_t)img*POST+o)*5;
    if(o<c){
      int r=list[o];
      const float* b=sbox+((size_t)img*KTOT+r)*4;
      row[0]=b[0]; row[1]=b[1]; row[2]=b[2]; row[3]=b[3];
      row[4]=sscore[img*KTOT+r];
    } else {
      row[0]=0.f; row[1]=0.f; row[2]=0.f; row[3]=0.f; row[4]=0.f;
    }
  }
}

extern "C" void kernel_launch(void* const* d_in, const int* in_sizes, int n_in,
                              void* d_out, int out_size, void* d_ws, size_t ws_size,
                              hipStream_t stream){
  const float* obj=(const float*)d_in[0];
  const float* del=(const float*)d_in[1];
  const float* anc=(const float*)d_in[2];
  float* out=(float*)d_out;

  char* w=(char*)d_ws;
  size_t off=0;
  auto alloc=[&](size_t bytes)->void*{
    void* p=w+off; off+=(bytes+255)&~(size_t)255; return p;
  };
  int*  sel    =(int*)  alloc(sizeof(int)*NIMG*KTOT);
  float* pbox  =(float*)alloc(sizeof(float)*NIMG*KTOT*4);
  float* pscore=(float*)alloc(sizeof(float)*NIMG*KTOT);
  int*  plvl   =(int*)  alloc(sizeof(int)*NIMG*KTOT);
  unsigned long long* gkey=(unsigned long long*)alloc(sizeof(unsigned long long)*NIMG*KTOT);
  float* sbox  =(float*)alloc(sizeof(float)*NIMG*KTOT*4);
  float* sscore=(float*)alloc(sizeof(float)*NIMG*KTOT);
  int*  slvl   =(int*)  alloc(sizeof(int)*NIMG*KTOT);
  int*  ssupp  =(int*)  alloc(sizeof(int)*NIMG*KTOT);
  float* gmax  =(float*)alloc(sizeof(float)*NIMG);
  int*  eqbuf  =(int*)  alloc(sizeof(int)*40*2048);
  int*  lists  =(int*)  alloc(sizeof(int)*40*1024);
  int*  mcnt   =(int*)  alloc(sizeof(int)*40);
  float4* nbox =(float4*)alloc(sizeof(float4)*40*1024);
  float* narea =(float*)alloc(sizeof(float)*40*1024);
  unsigned long long* mask=(unsigned long long*)alloc(sizeof(unsigned long long)*40*1024*16);
  unsigned* ghist=(unsigned*)alloc(sizeof(unsigned)*40*2048);
  unsigned* gpref=(unsigned*)alloc(sizeof(unsigned)*40);
  int*  gkrem  =(int*)  alloc(sizeof(int)*40);
  int*  gcnt   =(int*)  alloc(sizeof(int)*80);
  int*  grank  =(int*)  alloc(sizeof(int)*NIMG*KTOT);

  hipLaunchKernelGGL(k_zero,    dim3((40*2048+NIMG*KTOT+255)/256), dim3(256), 0, stream,
                     ghist, grank);
  hipLaunchKernelGGL(k_hist<0>, dim3(40,NSUB), dim3(256), 0, stream, obj, gpref, ghist);
  hipLaunchKernelGGL(k_scan<0>, dim3(40), dim3(256), 0, stream, ghist, gpref, gkrem, gcnt);
  hipLaunchKernelGGL(k_hist<1>, dim3(40,NSUB), dim3(256), 0, stream, obj, gpref, ghist);
  hipLaunchKernelGGL(k_scan<1>, dim3(40), dim3(256), 0, stream, ghist, gpref, gkrem, gcnt);
  hipLaunchKernelGGL(k_hist<2>, dim3(40,NSUB), dim3(256), 0, stream, obj, gpref, ghist);
  hipLaunchKernelGGL(k_scan<2>, dim3(40), dim3(256), 0, stream, ghist, gpref, gkrem, gcnt);
  hipLaunchKernelGGL(k_sel,    dim3(40,NSUB), dim3(256), 0, stream, obj, gpref, gkrem,
                     gcnt, sel, eqbuf);
  hipLaunchKernelGGL(k_sort,   dim3(40), dim3(256), 0, stream, obj, gkrem, gcnt, sel, eqbuf);
  hipLaunchKernelGGL(k_decode, dim3(NIMG), dim3(256), 0, stream, obj, del, anc, sel,
                     pbox, pscore, plvl, gkey, gmax);
  hipLaunchKernelGGL(k_rankp,  dim3(NIMG,18,18), dim3(256), 0, stream, gkey, grank);
  hipLaunchKernelGGL(k_scatter,dim3(NIMG*18), dim3(256), 0, stream, grank,
                     (const float4*)pbox, pscore, plvl,
                     (float4*)sbox, sscore, slvl, ssupp);
  hipLaunchKernelGGL(k_list,   dim3(40), dim3(256), 0, stream, sbox, slvl, ssupp, gmax,
                     lists, mcnt, nbox, narea);
  hipLaunchKernelGGL(k_mask,   dim3(40,64), dim3(256), 0, stream, nbox, narea, mcnt, mask);
  hipLaunchKernelGGL(k_reduce, dim3(40), dim3(256), 0, stream, mask, mcnt, lists, ssupp);
  hipLaunchKernelGGL(k_out,    dim3(NIMG), dim3(256), 0, stream, sbox, sscore, ssupp, out);
}

// Round 10
// 244.031 us; speedup vs baseline: 1.2003x; 1.2003x over previous
//
#include <hip/hip_runtime.h>
#include <math.h>

#define NIMG 8
#define TT   159882
#define KTOT 4507
#define POST 1000
#define NSUB 32

__constant__ int c_n[5]   = {120000,30000,7500,1875,507};
__constant__ int c_off[5] = {0,120000,150000,157500,159375};
__constant__ int c_k[5]   = {1000,1000,1000,1000,507};
__constant__ int c_pos[5] = {0,1000,2000,3000,4000};

__device__ __forceinline__ unsigned fkey(float f){
  unsigned u=__float_as_uint(f);
  return (u&0x80000000u)? ~u : (u|0x80000000u);
}

// ---------------- K0: zero global histograms + rank array + gmax --------------
__global__ __launch_bounds__(256) void k_zero(unsigned* __restrict__ ghist,
                                              int* __restrict__ grank,
                                              unsigned* __restrict__ gmaxu){
  int i=blockIdx.x*256+threadIdx.x;
  if(i<40*2048) ghist[i]=0u;
  int j=i-40*2048;
  if(j>=0 && j<NIMG*KTOT) grank[j]=0;
  int j2=j-NIMG*KTOT;
  if(j2>=0 && j2<NIMG) gmaxu[j2]=0u;
}

// ---------------- K1a: distributed radix histogram (one round) ----------------
template<int RND>
__global__ __launch_bounds__(256) void k_hist(const float* __restrict__ obj,
    const unsigned* __restrict__ gpref, unsigned* __restrict__ ghist){
  constexpr int sh=(RND==0)?21:(RND==1)?10:0;
  constexpr int nb=(RND==2)?1024:2048;
  constexpr unsigned msk=(unsigned)(nb-1);
  const int il=blockIdx.x, sub=blockIdx.y;
  const int img=il/5, lvl=il%5;
  const int n=c_n[lvl], k=c_k[lvl];
  if(k>=n) return;
  const int chunk=(n+NSUB-1)/NSUB;
  const int start=sub*chunk, end=min(start+chunk,n);
  if(start>=end) return;
  const float* o=obj+(size_t)img*TT+c_off[lvl];
  __shared__ unsigned hist[2048];
  const unsigned prefix=(RND==0)?0u:gpref[il];
  for(int i=threadIdx.x;i<nb;i+=256) hist[i]=0u;
  __syncthreads();
  for(int i=start+threadIdx.x;i<end;i+=256){
    unsigned key=fkey(o[i]);
    if(RND==0){
      atomicAdd(&hist[(key>>sh)&msk],1u);
    } else {
      constexpr unsigned hiMask=0xFFFFFFFFu<<((RND==1)?21:10);
      if((key&hiMask)==prefix) atomicAdd(&hist[(key>>sh)&msk],1u);
    }
  }
  __syncthreads();
  for(int b=threadIdx.x;b<nb;b+=256){
    unsigned v=hist[b];
    if(v) atomicAdd(&ghist[il*2048+b],v);
  }
}

// ---------------- K1b: pick bucket via register suffix-sum + LDS tree ---------
template<int RND>
__global__ __launch_bounds__(256) void k_scan(unsigned* __restrict__ ghist,
    unsigned* __restrict__ gpref, int* __restrict__ gkrem,
    int* __restrict__ gcnt){
  constexpr int sh=(RND==0)?21:(RND==1)?10:0;
  constexpr int nb=(RND==2)?1024:2048;
  constexpr int C=nb/256;
  const int il=blockIdx.x, lvl=il%5;
  const int n=c_n[lvl], k=c_k[lvl];
  const int t=threadIdx.x;
  __shared__ unsigned tot[256];
  if(k>=n){
    if(RND==2 && t==0){ gpref[il]=0u; gkrem[il]=0; gcnt[il*2]=0; gcnt[il*2+1]=0; }
    return;
  }
  const int kr=(RND==0)?k:gkrem[il];
  unsigned v[C];
#pragma unroll
  for(int i=0;i<C;i++) v[i]=ghist[il*2048+t*C+i];
#pragma unroll
  for(int i=C-2;i>=0;i--) v[i]+=v[i+1];          // local suffix sum (registers)
  tot[t]=v[0];
  __syncthreads();
#pragma unroll
  for(int d=1;d<256;d<<=1){                       // inclusive suffix scan of totals
    unsigned add=(t+d<256)?tot[t+d]:0u;
    __syncthreads();
    tot[t]+=add;
    __syncthreads();
  }
  unsigned tail=(t<255)?tot[t+1]:0u;
#pragma unroll
  for(int i=0;i<C;i++){
    unsigned suf=v[i]+tail;
    unsigned sufn=((i<C-1)?v[i+1]:0u)+tail;
    if(suf>=(unsigned)kr && sufn<(unsigned)kr){
      unsigned prevPref=(RND==0)?0u:gpref[il];
      gpref[il]=prevPref|((unsigned)(t*C+i)<<sh);
      gkrem[il]=kr-(int)sufn;
    }
  }
  for(int b=t;b<2048;b+=256) ghist[il*2048+b]=0u; // ready for next round/replay
  if(RND==2 && t==0){ gcnt[il*2]=0; gcnt[il*2+1]=0; }
}

// ---------------- K1c: distributed selection against final threshold ---------
__global__ __launch_bounds__(256) void k_sel(const float* __restrict__ obj,
    const unsigned* __restrict__ gpref, const int* __restrict__ gkrem,
    int* __restrict__ gcnt, int* __restrict__ sel, int* __restrict__ eqbuf){
  const int il=blockIdx.x, sub=blockIdx.y;
  const int img=il/5, lvl=il%5;
  const int n=c_n[lvl], k=c_k[lvl];
  const int chunk=(n+NSUB-1)/NSUB;
  const int start=sub*chunk, end=min(start+chunk,n);
  if(start>=end) return;
  int* s=sel+img*KTOT+c_pos[lvl];
  if(k>=n){
    for(int i=start+threadIdx.x;i<end;i+=256) s[i]=i;
    return;
  }
  const float* o=obj+(size_t)img*TT+c_off[lvl];
  const unsigned t=gpref[il];
  const int krem=gkrem[il];
  for(int i=start+threadIdx.x;i<end;i+=256){
    unsigned key=fkey(o[i]);
    if(key>t){ s[atomicAdd(&gcnt[il*2],1)]=i; }
    else if(key==t && krem>0){ int p=atomicAdd(&gcnt[il*2+1],1); if(p<2048) eqbuf[il*2048+p]=i; }
  }
}

// ---------------- K1d: eq-tiebreak picks + level rank sort --------------------
__global__ __launch_bounds__(256) void k_sort(const float* __restrict__ obj,
    const int* __restrict__ gkrem, const int* __restrict__ gcnt,
    int* __restrict__ sel, int* __restrict__ eqbuf){
  const int il=blockIdx.x, img=il/5, lvl=il%5;
  const int n=c_n[lvl], k=c_k[lvl];
  const float* o=obj+(size_t)img*TT+c_off[lvl];
  int* s=sel+img*KTOT+c_pos[lvl];
  __shared__ unsigned long long skey[1024];
  if(k<n){
    const int krem=gkrem[il];
    if(krem>0 && threadIdx.x==0){
      int cgt=gcnt[il*2];
      int ceq=min(gcnt[il*2+1],2048);
      int* eq=eqbuf+il*2048;
      for(int r2=0;r2<krem;r2++){
        int mn=0x7fffffff,mi=0;
        for(int j=0;j<ceq;j++) if(eq[j]<mn){mn=eq[j];mi=j;}
        s[cgt+r2]=mn; eq[mi]=0x7fffffff;
      }
    }
    __syncthreads();
  }
  for(int i=threadIdx.x;i<k;i+=256){
    int idx=s[i];
    skey[i]=((unsigned long long)fkey(o[idx])<<32)|(unsigned)(~(unsigned)idx);
  }
  __syncthreads();
  for(int i=threadIdx.x;i<k;i+=256){
    unsigned long long mk=skey[i];
    int rank=0;
    for(int j=0;j<k;j++) rank+=(skey[j]>mk)?1:0;
    int idx=(int)(~(unsigned)(mk&0xFFFFFFFFu));
    s[rank]=idx+c_off[lvl];
  }
}

// ---------------- K2a: decode+clip+score; 144 blocks, atomicMax image max -----
__global__ __launch_bounds__(256) void k_decode(const float* __restrict__ obj,
    const float* __restrict__ del, const float* __restrict__ anc,
    const int* __restrict__ sel, float* __restrict__ pbox, float* __restrict__ pscore,
    int* __restrict__ plvl, unsigned long long* __restrict__ gkey,
    unsigned* __restrict__ gmaxu){
  const int img=blockIdx.x/18, chunk=blockIdx.x%18;
  const int pos=chunk*256+threadIdx.x;
  __shared__ float smax[256];
  const float BCLIP=(float)4.135166556742356;  // log(1000/16)
  float lm=0.f;
  if(pos<KTOT){
    int lvl = pos<1000?0:pos<2000?1:pos<3000?2:pos<4000?3:4;
    int tdx = sel[img*KTOT+pos];
    float logit = obj[(size_t)img*TT+tdx];
    const float* a=anc+4*(size_t)tdx;
    const float* d=del+((size_t)img*TT+tdx)*4;
    float w=a[2]-a[0], h=a[3]-a[1];
    float cx=a[0]+0.5f*w, cy=a[1]+0.5f*h;
    float dw=fminf(d[2],BCLIP), dh=fminf(d[3],BCLIP);
    float pcx=d[0]*w+cx, pcy=d[1]*h+cy;
    float pw=expf(dw)*w, ph=expf(dh)*h;
    float x1=pcx-0.5f*pw, y1=pcy-0.5f*ph;
    float x2=pcx+0.5f*pw, y2=pcy+0.5f*ph;
    x1=fminf(fmaxf(x1,0.f),800.f); y1=fminf(fmaxf(y1,0.f),800.f);
    x2=fminf(fmaxf(x2,0.f),800.f); y2=fminf(fmaxf(y2,0.f),800.f);
    int valid=(x2-x1>=1e-3f)&&(y2-y1>=1e-3f);
    float sc=1.f/(1.f+expf(-logit));
    float sv=valid? sc : -INFINITY;
    gkey[img*KTOT+pos]=((unsigned long long)fkey(sv)<<32)|(unsigned)(KTOT-1-pos);
    float* pb=pbox+((size_t)img*KTOT+pos)*4;
    pb[0]=x1; pb[1]=y1; pb[2]=x2; pb[3]=y2;
    pscore[img*KTOT+pos]=sc;
    plvl[img*KTOT+pos]=lvl|(valid?0:256);
    lm=fmaxf(fmaxf(x1,y1),fmaxf(x2,y2));
  }
  smax[threadIdx.x]=lm; __syncthreads();
  for(int st=128;st>0;st>>=1){
    if(threadIdx.x<st) smax[threadIdx.x]=fmaxf(smax[threadIdx.x],smax[threadIdx.x+st]);
    __syncthreads();
  }
  // coords >= 0, so u32 compare == float compare; max over all blocks is exact
  if(threadIdx.x==0) atomicMax(&gmaxu[img], __float_as_uint(smax[0]));
}

// ---------------- K2b: partial rank counts, 256x256 tiles ---------------------
__global__ __launch_bounds__(256) void k_rankp(const unsigned long long* __restrict__ gkey,
    int* __restrict__ grank){
  const int img=blockIdx.x, ic=blockIdx.y, jc=blockIdx.z;
  __shared__ unsigned long long sk[256];
  const int jbase=jc*256;
  const int jend=min(256, KTOT-jbase);
  const int i=ic*256+threadIdx.x;
  if(threadIdx.x<jend) sk[threadIdx.x]=gkey[img*KTOT+jbase+threadIdx.x];
  __syncthreads();
  if(i>=KTOT) return;
  const unsigned long long mk=gkey[img*KTOT+i];
  int r=0;
  #pragma unroll 4
  for(int j=0;j<jend;j++) r+=(sk[j]>mk)?1:0;
  if(r) atomicAdd(&grank[img*KTOT+i], r);
}

// ---------------- K2c: scatter by rank ---------------------------------------
__global__ __launch_bounds__(256) void k_scatter(const int* __restrict__ grank,
    const float4* __restrict__ pbox, const float* __restrict__ pscore,
    const int* __restrict__ plvl,
    float4* __restrict__ sbox, float* __restrict__ sscore,
    int* __restrict__ slvl, int* __restrict__ ssupp){
  const int img=blockIdx.x/18, chunk=blockIdx.x%18;
  const int pos=chunk*256+threadIdx.x;
  if(pos>=KTOT) return;
  const int rank=grank[img*KTOT+pos];
  sbox[(size_t)img*KTOT+rank]=pbox[(size_t)img*KTOT+pos];
  sscore[img*KTOT+rank]=pscore[img*KTOT+pos];
  int lv=plvl[img*KTOT+pos];
  slvl[img*KTOT+rank]=lv&0xFF;
  ssupp[img*KTOT+rank]=(lv>>8)&1;   // invalid -> pre-suppressed
}

// ---------------- K3a: candidate list; LDS-staged predicate, wave-0 ballot ----
__global__ __launch_bounds__(256) void k_list(const float* __restrict__ sbox,
    const int* __restrict__ slvl, const int* __restrict__ ssupp,
    const unsigned* __restrict__ gmaxu,
    int* __restrict__ lists, int* __restrict__ mcnt,
    float4* __restrict__ nbox, float* __restrict__ narea){
  const int img=blockIdx.x/5, lvl=blockIdx.x%5;
  const int tid=threadIdx.x;
  __shared__ unsigned char s_ok[KTOT];
  __shared__ int s_list[1024];
  __shared__ int s_m;
  for(int i=tid;i<KTOT;i+=256)
    s_ok[i]=(slvl[img*KTOT+i]==lvl && ssupp[img*KTOT+i]==0)?1:0;
  __syncthreads();
  if(tid<64){
    int base=0;
    for(int t=0;t<KTOT;t+=64){
      int r=t+tid;
      bool pred=(r<KTOT) && s_ok[r];
      unsigned long long b=__ballot(pred);
      int pre=__popcll(b & ((1ull<<tid)-1ull));
      if(pred) s_list[base+pre]=r;
      base+=__popcll(b);
    }
    if(tid==0){ s_m=base; mcnt[blockIdx.x]=base; }
  }
  __syncthreads();
  const int m=s_m;
  const float off=(float)lvl*(__uint_as_float(gmaxu[img])+1.0f);  // ref offset math
  const float4* sb4=(const float4*)sbox;
  for(int i=tid;i<m;i+=256){
    int r=s_list[i];
    lists[blockIdx.x*1024+i]=r;
    float4 bx=sb4[(size_t)img*KTOT+r];
    float a0=bx.x+off, a1=bx.y+off, a2=bx.z+off, a3=bx.w+off;
    nbox[blockIdx.x*1024+i]=make_float4(a0,a1,a2,a3);
    narea[blockIdx.x*1024+i]=(a2-a0)*(a3-a1);
  }
}

// ---------------- K3b: pairwise suppression bitmasks, 1 word/thread ------------
__global__ __launch_bounds__(256) void k_mask(const float4* __restrict__ nbox,
    const float* __restrict__ narea, const int* __restrict__ mcnt,
    unsigned long long* __restrict__ mask){
  const int il=blockIdx.x;
  const int rc=blockIdx.y>>4, w=blockIdx.y&15;
  const int m=mcnt[il];
  const int r0=rc*256;
  if(r0>=m) return;
  const int i=r0+threadIdx.x;
  const int wlast=(m+63)>>6;
  __shared__ float4 sb[64];
  __shared__ float  sa[64];
  unsigned long long bits=0ull;
  const bool block_active = (w>=rc*4) && (w<wlast);   // rc*4 == min wi in block
  if(block_active){
    const int jend=min(64, m-w*64);
    if(threadIdx.x<64 && threadIdx.x<jend){
      sb[threadIdx.x]=nbox[il*1024+w*64+threadIdx.x];
      sa[threadIdx.x]=narea[il*1024+w*64+threadIdx.x];
    }
    __syncthreads();
    const int wi=i>>6;
    if(i<m && w>=wi){
      const float4 bi=nbox[il*1024+i];
      const float  ai=narea[il*1024+i];
      for(int jj=0;jj<jend;++jj){
        const float4 bj=sb[jj];                 // LDS broadcast
        float ltx=fmaxf(bi.x,bj.x), lty=fmaxf(bi.y,bj.y);
        float rbx=fminf(bi.z,bj.z), rby=fminf(bi.w,bj.w);
        float wx=fmaxf(rbx-ltx,0.f), wy=fmaxf(rby-lty,0.f);
        float inter=wx*wy;
        float iou=inter/((ai+sa[jj])-inter);
        bits |= (iou>0.7f)? (1ull<<jj) : 0ull;
      }
      if(w==wi){ int b=i&63; bits &= ~((2ull<<b)-1ull); }  // keep only j>i
    }
  }
  if(i<m) mask[((size_t)il*1024+i)*16+w]=bits;
}

// ---------------- K3c: greedy reduce; unconditional ds_reads (padded rows) ----
__global__ __launch_bounds__(256) void k_reduce(const unsigned long long* __restrict__ mask,
    const int* __restrict__ mcnt, const int* __restrict__ lists,
    int* __restrict__ ssupp){
  const int il=blockIdx.x, img=il/5;
  const int m=mcnt[il];
  const int m_pad=(m+15)&~15;
  __shared__ unsigned long long smask[1024*16];   // 128 KB slab
  // cooperative global->LDS copy, 8 loads in flight per thread, no tail loop
  {
    const float4* g4=(const float4*)(mask + (size_t)il*1024*16);
    float4* l4=(float4*)smask;
    const int tot4=(m*8+2047)&~2047;              // <= 8192 always (m<=1000)
    for(int i=threadIdx.x;i<tot4;i+=2048){
      float4 r0=g4[i      ], r1=g4[i+ 256], r2=g4[i+ 512], r3=g4[i+ 768];
      float4 r4=g4[i+1024], r5=g4[i+1280], r6=g4[i+1536], r7=g4[i+1792];
      l4[i      ]=r0; l4[i+ 256]=r1; l4[i+ 512]=r2; l4[i+ 768]=r3;
      l4[i+1024]=r4; l4[i+1280]=r5; l4[i+1536]=r6; l4[i+1792]=r7;
    }
  }
  __syncthreads();
  // zero-pad rows [m, m_pad) so the walk needs no bounds checks
  if(threadIdx.x<(m_pad-m)*16) smask[(unsigned)m*16+threadIdx.x]=0ull;
  __syncthreads();
  if(threadIdx.x>=64) return;
  const int lane=threadIdx.x;
  const int seg=lane&15;      // lanes 16+ mirror lanes 0-15 (LDS broadcast, free)
  unsigned long long remv=0ull;
  unsigned long long c0,c1,c2,c3,c4,c5,c6,c7,c8,c9,c10,c11,c12,c13,c14,c15;
  unsigned long long n0,n1,n2,n3,n4,n5,n6,n7,n8,n9,n10,n11,n12,n13,n14,n15;
#define LD(r,b) smask[(unsigned)((b)+(r))*16+seg]
  c0 =LD(0,0);  c1 =LD(1,0);  c2 =LD(2,0);  c3 =LD(3,0);
  c4 =LD(4,0);  c5 =LD(5,0);  c6 =LD(6,0);  c7 =LD(7,0);
  c8 =LD(8,0);  c9 =LD(9,0);  c10=LD(10,0); c11=LD(11,0);
  c12=LD(12,0); c13=LD(13,0); c14=LD(14,0); c15=LD(15,0);
  for(int g=0;;++g){
    const int nb=(g+1)*16;
    n0 =LD(0,nb);  n1 =LD(1,nb);  n2 =LD(2,nb);  n3 =LD(3,nb);
    n4 =LD(4,nb);  n5 =LD(5,nb);  n6 =LD(6,nb);  n7 =LD(7,nb);
    n8 =LD(8,nb);  n9 =LD(9,nb);  n10=LD(10,nb); n11=LD(11,nb);
    n12=LD(12,nb); n13=LD(13,nb); n14=LD(14,nb); n15=LD(15,nb);
    // lane-local simulated decisions; lane w authoritative (base%64 in {0,16,32,48})
    const int base=g*16;
    const int w=base>>6;          // wave-uniform, < 16
    const int bb=base&63;
    unsigned t8=(unsigned)(remv>>bb);
    unsigned am=0u;
#define DEC(r,cr) { unsigned alive=1u^((t8>>(r))&1u); am|=alive<<(r); \
                    if(alive) t8|=(unsigned)((cr)>>bb); }
    DEC(0,c0)  DEC(1,c1)  DEC(2,c2)  DEC(3,c3)
    DEC(4,c4)  DEC(5,c5)  DEC(6,c6)  DEC(7,c7)
    DEC(8,c8)  DEC(9,c9)  DEC(10,c10) DEC(11,c11)
    DEC(12,c12) DEC(13,c13) DEC(14,c14) DEC(15,c15)
#undef DEC
    unsigned am_w=__builtin_amdgcn_readlane(am, w);   // SALU path, no LDS op
#define APP(r,cr) { unsigned long long mk64=0ull-(unsigned long long)((am_w>>(r))&1u); \
                    remv|=(cr)&mk64; }
    APP(0,c0)  APP(1,c1)  APP(2,c2)  APP(3,c3)
    APP(4,c4)  APP(5,c5)  APP(6,c6)  APP(7,c7)
    APP(8,c8)  APP(9,c9)  APP(10,c10) APP(11,c11)
    APP(12,c12) APP(13,c13) APP(14,c14) APP(15,c15)
#undef APP
    if(nb>=m) break;
    c0 =n0;  c1 =n1;  c2 =n2;  c3 =n3;  c4 =n4;  c5 =n5;  c6 =n6;  c7 =n7;
    c8 =n8;  c9 =n9;  c10=n10; c11=n11; c12=n12; c13=n13; c14=n14; c15=n15;
  }
#undef LD
  const int* list = lists + il*1024;
  for(int t=0;t<m;t+=64){
    int i=t+lane;
    unsigned long long word=__shfl(remv, (i<m? i:0)>>6);
    if(i<m && ((word>>(i&63))&1ull)) ssupp[img*KTOT+list[i]]=1;
  }
}

// ---------------- K4: compact survivors; LDS-staged predicate -----------------
__global__ __launch_bounds__(256) void k_out(const float* __restrict__ sbox,
    const float* __restrict__ sscore, const int* __restrict__ ssupp,
    float* __restrict__ out){
  const int img=blockIdx.x;
  const int tid=threadIdx.x;
  __shared__ unsigned char s_ok[KTOT];
  __shared__ unsigned short list[POST];
  __shared__ int s_c;
  for(int i=tid;i<KTOT;i+=256) s_ok[i]=(ssupp[img*KTOT+i]==0)?1:0;
  __syncthreads();
  if(tid<64){
    int base=0;
    for(int t=0;t<KTOT && base<POST;t+=64){
      int r=t+tid;
      bool pred=(r<KTOT) && s_ok[r];
      unsigned long long b=__ballot(pred);
      int pre=__popcll(b & ((1ull<<tid)-1ull));
      if(pred && base+pre<POST) list[base+pre]=(unsigned short)r;
      base+=__popcll(b);
    }
    if(tid==0) s_c=min(base,POST);
  }
  __syncthreads();
  const int c=s_c;
  for(int o=tid;o<POST;o+=256){
    float* row=out+((size_t)img*POST+o)*5;
    if(o<c){
      int r=list[o];
      const float* b=sbox+((size_t)img*KTOT+r)*4;
      row[0]=b[0]; row[1]=b[1]; row[2]=b[2]; row[3]=b[3];
      row[4]=sscore[img*KTOT+r];
    } else {
      row[0]=0.f; row[1]=0.f; row[2]=0.f; row[3]=0.f; row[4]=0.f;
    }
  }
}

extern "C" void kernel_launch(void* const* d_in, const int* in_sizes, int n_in,
                              void* d_out, int out_size, void* d_ws, size_t ws_size,
                              hipStream_t stream){
  const float* obj=(const float*)d_in[0];
  const float* del=(const float*)d_in[1];
  const float* anc=(const float*)d_in[2];
  float* out=(float*)d_out;

  char* w=(char*)d_ws;
  size_t off=0;
  auto alloc=[&](size_t bytes)->void*{
    void* p=w+off; off+=(bytes+255)&~(size_t)255; return p;
  };
  int*  sel    =(int*)  alloc(sizeof(int)*NIMG*KTOT);
  float* pbox  =(float*)alloc(sizeof(float)*NIMG*KTOT*4);
  float* pscore=(float*)alloc(sizeof(float)*NIMG*KTOT);
  int*  plvl   =(int*)  alloc(sizeof(int)*NIMG*KTOT);
  unsigned long long* gkey=(unsigned long long*)alloc(sizeof(unsigned long long)*NIMG*KTOT);
  float* sbox  =(float*)alloc(sizeof(float)*NIMG*KTOT*4);
  float* sscore=(float*)alloc(sizeof(float)*NIMG*KTOT);
  int*  slvl   =(int*)  alloc(sizeof(int)*NIMG*KTOT);
  int*  ssupp  =(int*)  alloc(sizeof(int)*NIMG*KTOT);
  unsigned* gmaxu=(unsigned*)alloc(sizeof(unsigned)*NIMG);
  int*  eqbuf  =(int*)  alloc(sizeof(int)*40*2048);
  int*  lists  =(int*)  alloc(sizeof(int)*40*1024);
  int*  mcnt   =(int*)  alloc(sizeof(int)*40);
  float4* nbox =(float4*)alloc(sizeof(float4)*40*1024);
  float* narea =(float*)alloc(sizeof(float)*40*1024);
  unsigned long long* mask=(unsigned long long*)alloc(sizeof(unsigned long long)*40*1024*16);
  unsigned* ghist=(unsigned*)alloc(sizeof(unsigned)*40*2048);
  unsigned* gpref=(unsigned*)alloc(sizeof(unsigned)*40);
  int*  gkrem  =(int*)  alloc(sizeof(int)*40);
  int*  gcnt   =(int*)  alloc(sizeof(int)*80);
  int*  grank  =(int*)  alloc(sizeof(int)*NIMG*KTOT);

  hipLaunchKernelGGL(k_zero,    dim3((40*2048+NIMG*KTOT+NIMG+255)/256), dim3(256), 0, stream,
                     ghist, grank, gmaxu);
  hipLaunchKernelGGL(k_hist<0>, dim3(40,NSUB), dim3(256), 0, stream, obj, gpref, ghist);
  hipLaunchKernelGGL(k_scan<0>, dim3(40), dim3(256), 0, stream, ghist, gpref, gkrem, gcnt);
  hipLaunchKernelGGL(k_hist<1>, dim3(40,NSUB), dim3(256), 0, stream, obj, gpref, ghist);
  hipLaunchKernelGGL(k_scan<1>, dim3(40), dim3(256), 0, stream, ghist, gpref, gkrem, gcnt);
  hipLaunchKernelGGL(k_hist<2>, dim3(40,NSUB), dim3(256), 0, stream, obj, gpref, ghist);
  hipLaunchKernelGGL(k_scan<2>, dim3(40), dim3(256), 0, stream, ghist, gpref, gkrem, gcnt);
  hipLaunchKernelGGL(k_sel,    dim3(40,NSUB), dim3(256), 0, stream, obj, gpref, gkrem,
                     gcnt, sel, eqbuf);
  hipLaunchKernelGGL(k_sort,   dim3(40), dim3(256), 0, stream, obj, gkrem, gcnt, sel, eqbuf);
  hipLaunchKernelGGL(k_decode, dim3(NIMG*18), dim3(256), 0, stream, obj, del, anc, sel,
                     pbox, pscore, plvl, gkey, gmaxu);
  hipLaunchKernelGGL(k_rankp,  dim3(NIMG,18,18), dim3(256), 0, stream, gkey, grank);
  hipLaunchKernelGGL(k_scatter,dim3(NIMG*18), dim3(256), 0, stream, grank,
                     (const float4*)pbox, pscore, plvl,
                     (float4*)sbox, sscore, slvl, ssupp);
  hipLaunchKernelGGL(k_list,   dim3(40), dim3(256), 0, stream, sbox, slvl, ssupp, gmaxu,
                     lists, mcnt, nbox, narea);
  hipLaunchKernelGGL(k_mask,   dim3(40,64), dim3(256), 0, stream, nbox, narea, mcnt, mask);
  hipLaunchKernelGGL(k_reduce, dim3(40), dim3(256), 0, stream, mask, mcnt, lists, ssupp);
  hipLaunchKernelGGL(k_out,    dim3(NIMG), dim3(256), 0, stream, sbox, sscore, ssupp, out);
}

// Round 11
// 199.284 us; speedup vs baseline: 1.4698x; 1.2245x over previous
//
#include <hip/hip_runtime.h>
#include <math.h>

#define NIMG 8
#define TT   159882
#define KTOT 4507
#define POST 1000
#define NSUB 32

__constant__ int c_n[5]   = {120000,30000,7500,1875,507};
__constant__ int c_off[5] = {0,120000,150000,157500,159375};
__constant__ int c_k[5]   = {1000,1000,1000,1000,507};
__constant__ int c_pos[5] = {0,1000,2000,3000,4000};

__device__ __forceinline__ unsigned fkey(float f){
  unsigned u=__float_as_uint(f);
  return (u&0x80000000u)? ~u : (u|0x80000000u);
}

// ---------------- K0: zero global histograms + rank array + gmax --------------
__global__ __launch_bounds__(256) void k_zero(unsigned* __restrict__ ghist,
                                              int* __restrict__ grank,
                                              unsigned* __restrict__ gmaxu){
  int i=blockIdx.x*256+threadIdx.x;
  if(i<40*2048) ghist[i]=0u;
  int j=i-40*2048;
  if(j>=0 && j<NIMG*KTOT) grank[j]=0;
  int j2=j-NIMG*KTOT;
  if(j2>=0 && j2<NIMG) gmaxu[j2]=0u;
}

// ---------------- K1a: distributed radix histogram (one round) ----------------
template<int RND>
__global__ __launch_bounds__(256) void k_hist(const float* __restrict__ obj,
    const unsigned* __restrict__ gpref, unsigned* __restrict__ ghist){
  constexpr int sh=(RND==0)?21:(RND==1)?10:0;
  constexpr int nb=(RND==2)?1024:2048;
  constexpr unsigned msk=(unsigned)(nb-1);
  const int il=blockIdx.x, sub=blockIdx.y;
  const int img=il/5, lvl=il%5;
  const int n=c_n[lvl], k=c_k[lvl];
  if(k>=n) return;
  const int chunk=(n+NSUB-1)/NSUB;
  const int start=sub*chunk, end=min(start+chunk,n);
  if(start>=end) return;
  const float* o=obj+(size_t)img*TT+c_off[lvl];
  __shared__ unsigned hist[2048];
  const unsigned prefix=(RND==0)?0u:gpref[il];
  for(int i=threadIdx.x;i<nb;i+=256) hist[i]=0u;
  __syncthreads();
  for(int i=start+threadIdx.x;i<end;i+=256){
    unsigned key=fkey(o[i]);
    if(RND==0){
      atomicAdd(&hist[(key>>sh)&msk],1u);
    } else {
      constexpr unsigned hiMask=0xFFFFFFFFu<<((RND==1)?21:10);
      if((key&hiMask)==prefix) atomicAdd(&hist[(key>>sh)&msk],1u);
    }
  }
  __syncthreads();
  for(int b=threadIdx.x;b<nb;b+=256){
    unsigned v=hist[b];
    if(v) atomicAdd(&ghist[il*2048+b],v);
  }
}

// ---------------- K1b: pick bucket via register suffix-sum + LDS tree ---------
template<int RND>
__global__ __launch_bounds__(256) void k_scan(unsigned* __restrict__ ghist,
    unsigned* __restrict__ gpref, int* __restrict__ gkrem,
    int* __restrict__ gcnt){
  constexpr int sh=(RND==0)?21:(RND==1)?10:0;
  constexpr int nb=(RND==2)?1024:2048;
  constexpr int C=nb/256;
  const int il=blockIdx.x, lvl=il%5;
  const int n=c_n[lvl], k=c_k[lvl];
  const int t=threadIdx.x;
  __shared__ unsigned tot[256];
  if(k>=n){
    if(RND==2 && t==0){ gpref[il]=0u; gkrem[il]=0; gcnt[il*2]=0; gcnt[il*2+1]=0; }
    return;
  }
  const int kr=(RND==0)?k:gkrem[il];
  unsigned v[C];
#pragma unroll
  for(int i=0;i<C;i++) v[i]=ghist[il*2048+t*C+i];
#pragma unroll
  for(int i=C-2;i>=0;i--) v[i]+=v[i+1];          // local suffix sum (registers)
  tot[t]=v[0];
  __syncthreads();
#pragma unroll
  for(int d=1;d<256;d<<=1){                       // inclusive suffix scan of totals
    unsigned add=(t+d<256)?tot[t+d]:0u;
    __syncthreads();
    tot[t]+=add;
    __syncthreads();
  }
  unsigned tail=(t<255)?tot[t+1]:0u;
#pragma unroll
  for(int i=0;i<C;i++){
    unsigned suf=v[i]+tail;
    unsigned sufn=((i<C-1)?v[i+1]:0u)+tail;
    if(suf>=(unsigned)kr && sufn<(unsigned)kr){
      unsigned prevPref=(RND==0)?0u:gpref[il];
      gpref[il]=prevPref|((unsigned)(t*C+i)<<sh);
      gkrem[il]=kr-(int)sufn;
    }
  }
  for(int b=t;b<2048;b+=256) ghist[il*2048+b]=0u; // ready for next round/replay
  if(RND==2 && t==0){ gcnt[il*2]=0; gcnt[il*2+1]=0; }
}

// ---------------- K1c: distributed selection against final threshold ---------
__global__ __launch_bounds__(256) void k_sel(const float* __restrict__ obj,
    const unsigned* __restrict__ gpref, const int* __restrict__ gkrem,
    int* __restrict__ gcnt, int* __restrict__ sel, int* __restrict__ eqbuf){
  const int il=blockIdx.x, sub=blockIdx.y;
  const int img=il/5, lvl=il%5;
  const int n=c_n[lvl], k=c_k[lvl];
  const int chunk=(n+NSUB-1)/NSUB;
  const int start=sub*chunk, end=min(start+chunk,n);
  if(start>=end) return;
  int* s=sel+img*KTOT+c_pos[lvl];
  if(k>=n){
    for(int i=start+threadIdx.x;i<end;i+=256) s[i]=i;
    return;
  }
  const float* o=obj+(size_t)img*TT+c_off[lvl];
  const unsigned t=gpref[il];
  const int krem=gkrem[il];
  for(int i=start+threadIdx.x;i<end;i+=256){
    unsigned key=fkey(o[i]);
    if(key>t){ s[atomicAdd(&gcnt[il*2],1)]=i; }
    else if(key==t && krem>0){ int p=atomicAdd(&gcnt[il*2+1],1); if(p<2048) eqbuf[il*2048+p]=i; }
  }
}

// ---------------- K1d: distributed level rank-sort -> sel2 --------------------
// grid (40,4). Each block stages all k level keys in LDS (eq-tiebreak computed
// redundantly per block on an LDS copy of eqbuf -- no global mutation), then
// each thread ranks one key with an 8-wide batched LDS loop and scatters
// s2[rank]=idx+off. Rank is a bijection -> sel2 fully written.
__global__ __launch_bounds__(256) void k_sortd(const float* __restrict__ obj,
    const int* __restrict__ gkrem, const int* __restrict__ gcnt,
    const int* __restrict__ sel, int* __restrict__ sel2,
    const int* __restrict__ eqbuf){
  const int il=blockIdx.x, chunk=blockIdx.y;
  const int img=il/5, lvl=il%5;
  const int n=c_n[lvl], k=c_k[lvl];
  if(chunk*256>=k) return;
  const float* o=obj+(size_t)img*TT+c_off[lvl];
  const int* s=sel+img*KTOT+c_pos[lvl];
  int* s2=sel2+img*KTOT+c_pos[lvl];
  __shared__ unsigned long long skey[1024];
  __shared__ int eqls[2048];
  int cgt, krem;
  if(k<n){ cgt=gcnt[il*2]; krem=gkrem[il]; } else { cgt=k; krem=0; }
  const int ceq = (krem>0)? min(gcnt[il*2+1],2048) : 0;
  // stage non-eq keys + LDS copy of eq candidates
  for(int i=threadIdx.x;i<cgt;i+=256){
    int idx=s[i];
    skey[i]=((unsigned long long)fkey(o[idx])<<32)|(unsigned)(~(unsigned)idx);
  }
  for(int i=threadIdx.x;i<ceq;i+=256) eqls[i]=eqbuf[il*2048+i];
  __syncthreads();
  if(krem>0 && threadIdx.x==0){
    for(int r2=0;r2<krem;r2++){
      int mn=0x7fffffff,mi=0;
      for(int j=0;j<ceq;j++) if(eqls[j]<mn){mn=eqls[j];mi=j;}
      skey[cgt+r2]=((unsigned long long)fkey(o[mn])<<32)|(unsigned)(~(unsigned)mn);
      eqls[mi]=0x7fffffff;
    }
  }
  __syncthreads();
  const int i=chunk*256+threadIdx.x;
  if(i>=k) return;
  const unsigned long long mk=skey[i];
  int rank=0, j=0;
  const int k8=k&~7;
  for(;j<k8;j+=8){
    unsigned long long a0=skey[j  ],a1=skey[j+1],a2=skey[j+2],a3=skey[j+3];
    unsigned long long a4=skey[j+4],a5=skey[j+5],a6=skey[j+6],a7=skey[j+7];
    rank+=((a0>mk)?1:0)+((a1>mk)?1:0)+((a2>mk)?1:0)+((a3>mk)?1:0)
         +((a4>mk)?1:0)+((a5>mk)?1:0)+((a6>mk)?1:0)+((a7>mk)?1:0);
  }
  for(;j<k;j++) rank+=(skey[j]>mk)?1:0;
  int idx=(int)(~(unsigned)(mk&0xFFFFFFFFu));
  s2[rank]=idx+c_off[lvl];
}

// ---------------- K2a: decode+clip+score; 144 blocks, atomicMax image max -----
__global__ __launch_bounds__(256) void k_decode(const float* __restrict__ obj,
    const float* __restrict__ del, const float* __restrict__ anc,
    const int* __restrict__ sel, float* __restrict__ pbox, float* __restrict__ pscore,
    int* __restrict__ plvl, unsigned long long* __restrict__ gkey,
    unsigned* __restrict__ gmaxu){
  const int img=blockIdx.x/18, chunk=blockIdx.x%18;
  const int pos=chunk*256+threadIdx.x;
  __shared__ float smax[256];
  const float BCLIP=(float)4.135166556742356;  // log(1000/16)
  float lm=0.f;
  if(pos<KTOT){
    int lvl = pos<1000?0:pos<2000?1:pos<3000?2:pos<4000?3:4;
    int tdx = sel[img*KTOT+pos];
    float logit = obj[(size_t)img*TT+tdx];
    const float* a=anc+4*(size_t)tdx;
    const float* d=del+((size_t)img*TT+tdx)*4;
    float w=a[2]-a[0], h=a[3]-a[1];
    float cx=a[0]+0.5f*w, cy=a[1]+0.5f*h;
    float dw=fminf(d[2],BCLIP), dh=fminf(d[3],BCLIP);
    float pcx=d[0]*w+cx, pcy=d[1]*h+cy;
    float pw=expf(dw)*w, ph=expf(dh)*h;
    float x1=pcx-0.5f*pw, y1=pcy-0.5f*ph;
    float x2=pcx+0.5f*pw, y2=pcy+0.5f*ph;
    x1=fminf(fmaxf(x1,0.f),800.f); y1=fminf(fmaxf(y1,0.f),800.f);
    x2=fminf(fmaxf(x2,0.f),800.f); y2=fminf(fmaxf(y2,0.f),800.f);
    int valid=(x2-x1>=1e-3f)&&(y2-y1>=1e-3f);
    float sc=1.f/(1.f+expf(-logit));
    float sv=valid? sc : -INFINITY;
    gkey[img*KTOT+pos]=((unsigned long long)fkey(sv)<<32)|(unsigned)(KTOT-1-pos);
    float* pb=pbox+((size_t)img*KTOT+pos)*4;
    pb[0]=x1; pb[1]=y1; pb[2]=x2; pb[3]=y2;
    pscore[img*KTOT+pos]=sc;
    plvl[img*KTOT+pos]=lvl|(valid?0:256);
    lm=fmaxf(fmaxf(x1,y1),fmaxf(x2,y2));
  }
  smax[threadIdx.x]=lm; __syncthreads();
  for(int st=128;st>0;st>>=1){
    if(threadIdx.x<st) smax[threadIdx.x]=fmaxf(smax[threadIdx.x],smax[threadIdx.x+st]);
    __syncthreads();
  }
  // coords >= 0, so u32 compare == float compare; max over all blocks is exact
  if(threadIdx.x==0) atomicMax(&gmaxu[img], __float_as_uint(smax[0]));
}

// ---------------- K2b: partial rank counts, 256x256 tiles ---------------------
__global__ __launch_bounds__(256) void k_rankp(const unsigned long long* __restrict__ gkey,
    int* __restrict__ grank){
  const int img=blockIdx.x, ic=blockIdx.y, jc=blockIdx.z;
  __shared__ unsigned long long sk[256];
  const int jbase=jc*256;
  const int jend=min(256, KTOT-jbase);
  const int i=ic*256+threadIdx.x;
  if(threadIdx.x<jend) sk[threadIdx.x]=gkey[img*KTOT+jbase+threadIdx.x];
  __syncthreads();
  if(i>=KTOT) return;
  const unsigned long long mk=gkey[img*KTOT+i];
  int r=0;
  #pragma unroll 4
  for(int j=0;j<jend;j++) r+=(sk[j]>mk)?1:0;
  if(r) atomicAdd(&grank[img*KTOT+i], r);
}

// ---------------- K2c: scatter by rank ---------------------------------------
__global__ __launch_bounds__(256) void k_scatter(const int* __restrict__ grank,
    const float4* __restrict__ pbox, const float* __restrict__ pscore,
    const int* __restrict__ plvl,
    float4* __restrict__ sbox, float* __restrict__ sscore,
    int* __restrict__ slvl, int* __restrict__ ssupp){
  const int img=blockIdx.x/18, chunk=blockIdx.x%18;
  const int pos=chunk*256+threadIdx.x;
  if(pos>=KTOT) return;
  const int rank=grank[img*KTOT+pos];
  sbox[(size_t)img*KTOT+rank]=pbox[(size_t)img*KTOT+pos];
  sscore[img*KTOT+rank]=pscore[img*KTOT+pos];
  int lv=plvl[img*KTOT+pos];
  slvl[img*KTOT+rank]=lv&0xFF;
  ssupp[img*KTOT+rank]=(lv>>8)&1;   // invalid -> pre-suppressed
}

// ---------------- K3a: candidate list; LDS-staged predicate, wave-0 ballot ----
__global__ __launch_bounds__(256) void k_list(const float* __restrict__ sbox,
    const int* __restrict__ slvl, const int* __restrict__ ssupp,
    const unsigned* __restrict__ gmaxu,
    int* __restrict__ lists, int* __restrict__ mcnt,
    float4* __restrict__ nbox, float* __restrict__ narea){
  const int img=blockIdx.x/5, lvl=blockIdx.x%5;
  const int tid=threadIdx.x;
  __shared__ unsigned char s_ok[KTOT];
  __shared__ int s_list[1024];
  __shared__ int s_m;
  for(int i=tid;i<KTOT;i+=256)
    s_ok[i]=(slvl[img*KTOT+i]==lvl && ssupp[img*KTOT+i]==0)?1:0;
  __syncthreads();
  if(tid<64){
    int base=0;
    for(int t=0;t<KTOT;t+=64){
      int r=t+tid;
      bool pred=(r<KTOT) && s_ok[r];
      unsigned long long b=__ballot(pred);
      int pre=__popcll(b & ((1ull<<tid)-1ull));
      if(pred) s_list[base+pre]=r;
      base+=__popcll(b);
    }
    if(tid==0){ s_m=base; mcnt[blockIdx.x]=base; }
  }
  __syncthreads();
  const int m=s_m;
  const float off=(float)lvl*(__uint_as_float(gmaxu[img])+1.0f);  // ref offset math
  const float4* sb4=(const float4*)sbox;
  for(int i=tid;i<m;i+=256){
    int r=s_list[i];
    lists[blockIdx.x*1024+i]=r;
    float4 bx=sb4[(size_t)img*KTOT+r];
    float a0=bx.x+off, a1=bx.y+off, a2=bx.z+off, a3=bx.w+off;
    nbox[blockIdx.x*1024+i]=make_float4(a0,a1,a2,a3);
    narea[blockIdx.x*1024+i]=(a2-a0)*(a3-a1);
  }
}

// ---------------- K3b: pairwise suppression bitmasks, 1 word/thread ------------
__global__ __launch_bounds__(256) void k_mask(const float4* __restrict__ nbox,
    const float* __restrict__ narea, const int* __restrict__ mcnt,
    unsigned long long* __restrict__ mask){
  const int il=blockIdx.x;
  const int rc=blockIdx.y>>4, w=blockIdx.y&15;
  const int m=mcnt[il];
  const int r0=rc*256;
  if(r0>=m) return;
  const int i=r0+threadIdx.x;
  const int wlast=(m+63)>>6;
  __shared__ float4 sb[64];
  __shared__ float  sa[64];
  unsigned long long bits=0ull;
  const bool block_active = (w>=rc*4) && (w<wlast);   // rc*4 == min wi in block
  if(block_active){
    const int jend=min(64, m-w*64);
    if(threadIdx.x<64 && threadIdx.x<jend){
      sb[threadIdx.x]=nbox[il*1024+w*64+threadIdx.x];
      sa[threadIdx.x]=narea[il*1024+w*64+threadIdx.x];
    }
    __syncthreads();
    const int wi=i>>6;
    if(i<m && w>=wi){
      const float4 bi=nbox[il*1024+i];
      const float  ai=narea[il*1024+i];
      for(int jj=0;jj<jend;++jj){
        const float4 bj=sb[jj];                 // LDS broadcast
        float ltx=fmaxf(bi.x,bj.x), lty=fmaxf(bi.y,bj.y);
        float rbx=fminf(bi.z,bj.z), rby=fminf(bi.w,bj.w);
        float wx=fmaxf(rbx-ltx,0.f), wy=fmaxf(rby-lty,0.f);
        float inter=wx*wy;
        float iou=inter/((ai+sa[jj])-inter);
        bits |= (iou>0.7f)? (1ull<<jj) : 0ull;
      }
      if(w==wi){ int b=i&63; bits &= ~((2ull<<b)-1ull); }  // keep only j>i
    }
  }
  if(i<m) mask[((size_t)il*1024+i)*16+w]=bits;
}

// ---------------- K3c: greedy reduce; unconditional ds_reads (padded rows) ----
__global__ __launch_bounds__(256) void k_reduce(const unsigned long long* __restrict__ mask,
    const int* __restrict__ mcnt, const int* __restrict__ lists,
    int* __restrict__ ssupp){
  const int il=blockIdx.x, img=il/5;
  const int m=mcnt[il];
  const int m_pad=(m+15)&~15;
  __shared__ unsigned long long smask[1024*16];   // 128 KB slab
  // cooperative global->LDS copy, 8 loads in flight per thread, no tail loop
  {
    const float4* g4=(const float4*)(mask + (size_t)il*1024*16);
    float4* l4=(float4*)smask;
    const int tot4=(m*8+2047)&~2047;              // <= 8192 always (m<=1000)
    for(int i=threadIdx.x;i<tot4;i+=2048){
      float4 r0=g4[i      ], r1=g4[i+ 256], r2=g4[i+ 512], r3=g4[i+ 768];
      float4 r4=g4[i+1024], r5=g4[i+1280], r6=g4[i+1536], r7=g4[i+1792];
      l4[i      ]=r0; l4[i+ 256]=r1; l4[i+ 512]=r2; l4[i+ 768]=r3;
      l4[i+1024]=r4; l4[i+1280]=r5; l4[i+1536]=r6; l4[i+1792]=r7;
    }
  }
  __syncthreads();
  // zero-pad rows [m, m_pad) so the walk needs no bounds checks
  if(threadIdx.x<(m_pad-m)*16) smask[(unsigned)m*16+threadIdx.x]=0ull;
  __syncthreads();
  if(threadIdx.x>=64) return;
  const int lane=threadIdx.x;
  const int seg=lane&15;      // lanes 16+ mirror lanes 0-15 (LDS broadcast, free)
  unsigned long long remv=0ull;
  unsigned long long c0,c1,c2,c3,c4,c5,c6,c7,c8,c9,c10,c11,c12,c13,c14,c15;
  unsigned long long n0,n1,n2,n3,n4,n5,n6,n7,n8,n9,n10,n11,n12,n13,n14,n15;
#define LD(r,b) smask[(unsigned)((b)+(r))*16+seg]
  c0 =LD(0,0);  c1 =LD(1,0);  c2 =LD(2,0);  c3 =LD(3,0);
  c4 =LD(4,0);  c5 =LD(5,0);  c6 =LD(6,0);  c7 =LD(7,0);
  c8 =LD(8,0);  c9 =LD(9,0);  c10=LD(10,0); c11=LD(11,0);
  c12=LD(12,0); c13=LD(13,0); c14=LD(14,0); c15=LD(15,0);
  for(int g=0;;++g){
    const int nb=(g+1)*16;
    n0 =LD(0,nb);  n1 =LD(1,nb);  n2 =LD(2,nb);  n3 =LD(3,nb);
    n4 =LD(4,nb);  n5 =LD(5,nb);  n6 =LD(6,nb);  n7 =LD(7,nb);
    n8 =LD(8,nb);  n9 =LD(9,nb);  n10=LD(10,nb); n11=LD(11,nb);
    n12=LD(12,nb); n13=LD(13,nb); n14=LD(14,nb); n15=LD(15,nb);
    // lane-local simulated decisions; lane w authoritative (base%64 in {0,16,32,48})
    const int base=g*16;
    const int w=base>>6;          // wave-uniform, < 16
    const int bb=base&63;
    unsigned t8=(unsigned)(remv>>bb);
    unsigned am=0u;
#define DEC(r,cr) { unsigned alive=1u^((t8>>(r))&1u); am|=alive<<(r); \
                    if(alive) t8|=(unsigned)((cr)>>bb); }
    DEC(0,c0)  DEC(1,c1)  DEC(2,c2)  DEC(3,c3)
    DEC(4,c4)  DEC(5,c5)  DEC(6,c6)  DEC(7,c7)
    DEC(8,c8)  DEC(9,c9)  DEC(10,c10) DEC(11,c11)
    DEC(12,c12) DEC(13,c13) DEC(14,c14) DEC(15,c15)
#undef DEC
    unsigned am_w=__builtin_amdgcn_readlane(am, w);   // SALU path, no LDS op
#define APP(r,cr) { unsigned long long mk64=0ull-(unsigned long long)((am_w>>(r))&1u); \
                    remv|=(cr)&mk64; }
    APP(0,c0)  APP(1,c1)  APP(2,c2)  APP(3,c3)
    APP(4,c4)  APP(5,c5)  APP(6,c6)  APP(7,c7)
    APP(8,c8)  APP(9,c9)  APP(10,c10) APP(11,c11)
    APP(12,c12) APP(13,c13) APP(14,c14) APP(15,c15)
#undef APP
    if(nb>=m) break;
    c0 =n0;  c1 =n1;  c2 =n2;  c3 =n3;  c4 =n4;  c5 =n5;  c6 =n6;  c7 =n7;
    c8 =n8;  c9 =n9;  c10=n10; c11=n11; c12=n12; c13=n13; c14=n14; c15=n15;
  }
#undef LD
  const int* list = lists + il*1024;
  for(int t=0;t<m;t+=64){
    int i=t+lane;
    unsigned long long word=__shfl(remv, (i<m? i:0)>>6);
    if(i<m && ((word>>(i&63))&1ull)) ssupp[img*KTOT+list[i]]=1;
  }
}

// ---------------- K4: compact survivors; LDS-staged predicate -----------------
__global__ __launch_bounds__(256) void k_out(const float* __restrict__ sbox,
    const float* __restrict__ sscore, const int* __restrict__ ssupp,
    float* __restrict__ out){
  const int img=blockIdx.x;
  const int tid=threadIdx.x;
  __shared__ unsigned char s_ok[KTOT];
  __shared__ unsigned short list[POST];
  __shared__ int s_c;
  for(int i=tid;i<KTOT;i+=256) s_ok[i]=(ssupp[img*KTOT+i]==0)?1:0;
  __syncthreads();
  if(tid<64){
    int base=0;
    for(int t=0;t<KTOT && base<POST;t+=64){
      int r=t+tid;
      bool pred=(r<KTOT) && s_ok[r];
      unsigned long long b=__ballot(pred);
      int pre=__popcll(b & ((1ull<<tid)-1ull));
      if(pred && base+pre<POST) list[base+pre]=(unsigned short)r;
      base+=__popcll(b);
    }
    if(tid==0) s_c=min(base,POST);
  }
  __syncthreads();
  const int c=s_c;
  for(int o=tid;o<POST;o+=256){
    float* row=out+((size_t)img*POST+o)*5;
    if(o<c){
      int r=list[o];
      const float* b=sbox+((size_t)img*KTOT+r)*4;
      row[0]=b[0]; row[1]=b[1]; row[2]=b[2]; row[3]=b[3];
      row[4]=sscore[img*KTOT+r];
    } else {
      row[0]=0.f; row[1]=0.f; row[2]=0.f; row[3]=0.f; row[4]=0.f;
    }
  }
}

extern "C" void kernel_launch(void* const* d_in, const int* in_sizes, int n_in,
                              void* d_out, int out_size, void* d_ws, size_t ws_size,
                              hipStream_t stream){
  const float* obj=(const float*)d_in[0];
  const float* del=(const float*)d_in[1];
  const float* anc=(const float*)d_in[2];
  float* out=(float*)d_out;

  char* w=(char*)d_ws;
  size_t off=0;
  auto alloc=[&](size_t bytes)->void*{
    void* p=w+off; off+=(bytes+255)&~(size_t)255; return p;
  };
  int*  sel    =(int*)  alloc(sizeof(int)*NIMG*KTOT);
  int*  sel2   =(int*)  alloc(sizeof(int)*NIMG*KTOT);
  float* pbox  =(float*)alloc(sizeof(float)*NIMG*KTOT*4);
  float* pscore=(float*)alloc(sizeof(float)*NIMG*KTOT);
  int*  plvl   =(int*)  alloc(sizeof(int)*NIMG*KTOT);
  unsigned long long* gkey=(unsigned long long*)alloc(sizeof(unsigned long long)*NIMG*KTOT);
  float* sbox  =(float*)alloc(sizeof(float)*NIMG*KTOT*4);
  float* sscore=(float*)alloc(sizeof(float)*NIMG*KTOT);
  int*  slvl   =(int*)  alloc(sizeof(int)*NIMG*KTOT);
  int*  ssupp  =(int*)  alloc(sizeof(int)*NIMG*KTOT);
  unsigned* gmaxu=(unsigned*)alloc(sizeof(unsigned)*NIMG);
  int*  eqbuf  =(int*)  alloc(sizeof(int)*40*2048);
  int*  lists  =(int*)  alloc(sizeof(int)*40*1024);
  int*  mcnt   =(int*)  alloc(sizeof(int)*40);
  float4* nbox =(float4*)alloc(sizeof(float4)*40*1024);
  float* narea =(float*)alloc(sizeof(float)*40*1024);
  unsigned long long* mask=(unsigned long long*)alloc(sizeof(unsigned long long)*40*1024*16);
  unsigned* ghist=(unsigned*)alloc(sizeof(unsigned)*40*2048);
  unsigned* gpref=(unsigned*)alloc(sizeof(unsigned)*40);
  int*  gkrem  =(int*)  alloc(sizeof(int)*40);
  int*  gcnt   =(int*)  alloc(sizeof(int)*80);
  int*  grank  =(int*)  alloc(sizeof(int)*NIMG*KTOT);

  hipLaunchKernelGGL(k_zero,    dim3((40*2048+NIMG*KTOT+NIMG+255)/256), dim3(256), 0, stream,
                     ghist, grank, gmaxu);
  hipLaunchKernelGGL(k_hist<0>, dim3(40,NSUB), dim3(256), 0, stream, obj, gpref, ghist);
  hipLaunchKernelGGL(k_scan<0>, dim3(40), dim3(256), 0, stream, ghist, gpref, gkrem, gcnt);
  hipLaunchKernelGGL(k_hist<1>, dim3(40,NSUB), dim3(256), 0, stream, obj, gpref, ghist);
  hipLaunchKernelGGL(k_scan<1>, dim3(40), dim3(256), 0, stream, ghist, gpref, gkrem, gcnt);
  hipLaunchKernelGGL(k_hist<2>, dim3(40,NSUB), dim3(256), 0, stream, obj, gpref, ghist);
  hipLaunchKernelGGL(k_scan<2>, dim3(40), dim3(256), 0, stream, ghist, gpref, gkrem, gcnt);
  hipLaunchKernelGGL(k_sel,    dim3(40,NSUB), dim3(256), 0, stream, obj, gpref, gkrem,
                     gcnt, sel, eqbuf);
  hipLaunchKernelGGL(k_sortd,  dim3(40,4), dim3(256), 0, stream, obj, gkrem, gcnt,
                     sel, sel2, eqbuf);
  hipLaunchKernelGGL(k_decode, dim3(NIMG*18), dim3(256), 0, stream, obj, del, anc, sel2,
                     pbox, pscore, plvl, gkey, gmaxu);
  hipLaunchKernelGGL(k_rankp,  dim3(NIMG,18,18), dim3(256), 0, stream, gkey, grank);
  hipLaunchKernelGGL(k_scatter,dim3(NIMG*18), dim3(256), 0, stream, grank,
                     (const float4*)pbox, pscore, plvl,
                     (float4*)sbox, sscore, slvl, ssupp);
  hipLaunchKernelGGL(k_list,   dim3(40), dim3(256), 0, stream, sbox, slvl, ssupp, gmaxu,
                     lists, mcnt, nbox, narea);
  hipLaunchKernelGGL(k_mask,   dim3(40,64), dim3(256), 0, stream, nbox, narea, mcnt, mask);
  hipLaunchKernelGGL(k_reduce, dim3(40), dim3(256), 0, stream, mask, mcnt, lists, ssupp);
  hipLaunchKernelGGL(k_out,    dim3(NIMG), dim3(256), 0, stream, sbox, sscore, ssupp, out);
}

// Round 12
// 160.632 us; speedup vs baseline: 1.8235x; 1.2406x over previous
//
#include <hip/hip_runtime.h>
#include <math.h>

#define NIMG 8
#define TT   159882
#define KTOT 4507
#define POST 1000
#define NSUB 32

__constant__ int c_n[5]   = {120000,30000,7500,1875,507};
__constant__ int c_off[5] = {0,120000,150000,157500,159375};
__constant__ int c_k[5]   = {1000,1000,1000,1000,507};
__constant__ int c_pos[5] = {0,1000,2000,3000,4000};

__device__ __forceinline__ unsigned fkey(float f){
  unsigned u=__float_as_uint(f);
  return (u&0x80000000u)? ~u : (u|0x80000000u);
}

// ---------------- K0: zero global histograms + rank array + gmax --------------
__global__ __launch_bounds__(256) void k_zero(unsigned* __restrict__ ghist,
                                              int* __restrict__ grank,
                                              unsigned* __restrict__ gmaxu){
  int i=blockIdx.x*256+threadIdx.x;
  if(i<40*2048) ghist[i]=0u;
  int j=i-40*2048;
  if(j>=0 && j<NIMG*KTOT) grank[j]=0;
  int j2=j-NIMG*KTOT;
  if(j2>=0 && j2<NIMG) gmaxu[j2]=0u;
}

// ---------------- K1a: distributed radix histogram (one round) ----------------
template<int RND>
__global__ __launch_bounds__(256) void k_hist(const float* __restrict__ obj,
    const unsigned* __restrict__ gpref, unsigned* __restrict__ ghist){
  constexpr int sh=(RND==0)?21:(RND==1)?10:0;
  constexpr int nb=(RND==2)?1024:2048;
  constexpr unsigned msk=(unsigned)(nb-1);
  const int il=blockIdx.x, sub=blockIdx.y;
  const int img=il/5, lvl=il%5;
  const int n=c_n[lvl], k=c_k[lvl];
  if(k>=n) return;
  const int chunk=(n+NSUB-1)/NSUB;
  const int start=sub*chunk, end=min(start+chunk,n);
  if(start>=end) return;
  const float* o=obj+(size_t)img*TT+c_off[lvl];
  __shared__ unsigned hist[2048];
  const unsigned prefix=(RND==0)?0u:gpref[il];
  for(int i=threadIdx.x;i<nb;i+=256) hist[i]=0u;
  __syncthreads();
  for(int i=start+threadIdx.x;i<end;i+=256){
    unsigned key=fkey(o[i]);
    if(RND==0){
      atomicAdd(&hist[(key>>sh)&msk],1u);
    } else {
      constexpr unsigned hiMask=0xFFFFFFFFu<<((RND==1)?21:10);
      if((key&hiMask)==prefix) atomicAdd(&hist[(key>>sh)&msk],1u);
    }
  }
  __syncthreads();
  for(int b=threadIdx.x;b<nb;b+=256){
    unsigned v=hist[b];
    if(v) atomicAdd(&ghist[il*2048+b],v);
  }
}

// ---------------- K1b: pick bucket via register suffix-sum + LDS tree ---------
template<int RND>
__global__ __launch_bounds__(256) void k_scan(unsigned* __restrict__ ghist,
    unsigned* __restrict__ gpref, int* __restrict__ gkrem,
    int* __restrict__ gcnt){
  constexpr int sh=(RND==0)?21:(RND==1)?10:0;
  constexpr int nb=(RND==2)?1024:2048;
  constexpr int C=nb/256;
  const int il=blockIdx.x, lvl=il%5;
  const int n=c_n[lvl], k=c_k[lvl];
  const int t=threadIdx.x;
  __shared__ unsigned tot[256];
  if(k>=n){
    if(RND==2 && t==0){ gpref[il]=0u; gkrem[il]=0; gcnt[il*2]=0; gcnt[il*2+1]=0; }
    return;
  }
  const int kr=(RND==0)?k:gkrem[il];
  unsigned v[C];
#pragma unroll
  for(int i=0;i<C;i++) v[i]=ghist[il*2048+t*C+i];
#pragma unroll
  for(int i=C-2;i>=0;i--) v[i]+=v[i+1];          // local suffix sum (registers)
  tot[t]=v[0];
  __syncthreads();
#pragma unroll
  for(int d=1;d<256;d<<=1){                       // inclusive suffix scan of totals
    unsigned add=(t+d<256)?tot[t+d]:0u;
    __syncthreads();
    tot[t]+=add;
    __syncthreads();
  }
  unsigned tail=(t<255)?tot[t+1]:0u;
#pragma unroll
  for(int i=0;i<C;i++){
    unsigned suf=v[i]+tail;
    unsigned sufn=((i<C-1)?v[i+1]:0u)+tail;
    if(suf>=(unsigned)kr && sufn<(unsigned)kr){
      unsigned prevPref=(RND==0)?0u:gpref[il];
      gpref[il]=prevPref|((unsigned)(t*C+i)<<sh);
      gkrem[il]=kr-(int)sufn;
    }
  }
  for(int b=t;b<2048;b+=256) ghist[il*2048+b]=0u; // ready for next round/replay
  if(RND==2 && t==0){ gcnt[il*2]=0; gcnt[il*2+1]=0; }
}

// ---------------- K1c: selection; block-local LDS aggregation -----------------
// Inner loop uses only LDS atomics (loads pipeline freely); one global atomic
// per block reserves the output range. sel/eqbuf order is nondeterministic but
// downstream k_sortd is set-invariant, so the result is bit-identical.
__global__ __launch_bounds__(256) void k_sel(const float* __restrict__ obj,
    const unsigned* __restrict__ gpref, const int* __restrict__ gkrem,
    int* __restrict__ gcnt, int* __restrict__ sel, int* __restrict__ eqbuf){
  const int il=blockIdx.x, sub=blockIdx.y;
  const int img=il/5, lvl=il%5;
  const int n=c_n[lvl], k=c_k[lvl];
  const int chunk=(n+NSUB-1)/NSUB;
  const int start=sub*chunk, end=min(start+chunk,n);
  if(start>=end) return;
  int* s=sel+img*KTOT+c_pos[lvl];
  if(k>=n){
    for(int i=start+threadIdx.x;i<end;i+=256) s[i]=i;
    return;
  }
  __shared__ int s_gt[1024];     // block share of gt-list (total cgt <= 1000)
  __shared__ int s_eq[2048];
  __shared__ int cnt_gt, cnt_eq, base_gt, base_eq;
  if(threadIdx.x==0){ cnt_gt=0; cnt_eq=0; }
  __syncthreads();
  const float* o=obj+(size_t)img*TT+c_off[lvl];
  const unsigned t=gpref[il];
  const int krem=gkrem[il];
  for(int i=start+threadIdx.x;i<end;i+=256){
    unsigned key=fkey(o[i]);
    if(key>t){ int p=atomicAdd(&cnt_gt,1); s_gt[p]=i; }
    else if(key==t && krem>0){ int p=atomicAdd(&cnt_eq,1); if(p<2048) s_eq[p]=i; }
  }
  __syncthreads();
  const int cg=cnt_gt, ce=min(cnt_eq,2048);
  if(threadIdx.x==0) base_gt=(cg>0)? atomicAdd(&gcnt[il*2],cg) : 0;
  if(threadIdx.x==1) base_eq=(ce>0)? atomicAdd(&gcnt[il*2+1],ce) : 0;
  __syncthreads();
  for(int i=threadIdx.x;i<cg;i+=256) s[base_gt+i]=s_gt[i];
  for(int i=threadIdx.x;i<ce;i+=256){
    int p=base_eq+i;
    if(p<2048) eqbuf[il*2048+p]=s_eq[i];
  }
}

// ---------------- K1d: distributed level rank-sort -> sel2 --------------------
__global__ __launch_bounds__(256) void k_sortd(const float* __restrict__ obj,
    const int* __restrict__ gkrem, const int* __restrict__ gcnt,
    const int* __restrict__ sel, int* __restrict__ sel2,
    const int* __restrict__ eqbuf){
  const int il=blockIdx.x, chunk=blockIdx.y;
  const int img=il/5, lvl=il%5;
  const int n=c_n[lvl], k=c_k[lvl];
  if(chunk*256>=k) return;
  const float* o=obj+(size_t)img*TT+c_off[lvl];
  const int* s=sel+img*KTOT+c_pos[lvl];
  int* s2=sel2+img*KTOT+c_pos[lvl];
  __shared__ unsigned long long skey[1024];
  __shared__ int eqls[2048];
  int cgt, krem;
  if(k<n){ cgt=gcnt[il*2]; krem=gkrem[il]; } else { cgt=k; krem=0; }
  const int ceq = (krem>0)? min(gcnt[il*2+1],2048) : 0;
  for(int i=threadIdx.x;i<cgt;i+=256){
    int idx=s[i];
    skey[i]=((unsigned long long)fkey(o[idx])<<32)|(unsigned)(~(unsigned)idx);
  }
  for(int i=threadIdx.x;i<ceq;i+=256) eqls[i]=eqbuf[il*2048+i];
  __syncthreads();
  if(krem>0 && threadIdx.x==0){
    for(int r2=0;r2<krem;r2++){
      int mn=0x7fffffff,mi=0;
      for(int j=0;j<ceq;j++) if(eqls[j]<mn){mn=eqls[j];mi=j;}
      skey[cgt+r2]=((unsigned long long)fkey(o[mn])<<32)|(unsigned)(~(unsigned)mn);
      eqls[mi]=0x7fffffff;
    }
  }
  __syncthreads();
  const int i=chunk*256+threadIdx.x;
  if(i>=k) return;
  const unsigned long long mk=skey[i];
  int rank=0, j=0;
  const int k8=k&~7;
  for(;j<k8;j+=8){
    unsigned long long a0=skey[j  ],a1=skey[j+1],a2=skey[j+2],a3=skey[j+3];
    unsigned long long a4=skey[j+4],a5=skey[j+5],a6=skey[j+6],a7=skey[j+7];
    rank+=((a0>mk)?1:0)+((a1>mk)?1:0)+((a2>mk)?1:0)+((a3>mk)?1:0)
         +((a4>mk)?1:0)+((a5>mk)?1:0)+((a6>mk)?1:0)+((a7>mk)?1:0);
  }
  for(;j<k;j++) rank+=(skey[j]>mk)?1:0;
  int idx=(int)(~(unsigned)(mk&0xFFFFFFFFu));
  s2[rank]=idx+c_off[lvl];
}

// ---------------- K2a: decode+clip+score; 144 blocks, atomicMax image max -----
__global__ __launch_bounds__(256) void k_decode(const float* __restrict__ obj,
    const float* __restrict__ del, const float* __restrict__ anc,
    const int* __restrict__ sel, float* __restrict__ pbox, float* __restrict__ pscore,
    int* __restrict__ plvl, unsigned long long* __restrict__ gkey,
    unsigned* __restrict__ gmaxu){
  const int img=blockIdx.x/18, chunk=blockIdx.x%18;
  const int pos=chunk*256+threadIdx.x;
  __shared__ float smax[256];
  const float BCLIP=(float)4.135166556742356;  // log(1000/16)
  float lm=0.f;
  if(pos<KTOT){
    int lvl = pos<1000?0:pos<2000?1:pos<3000?2:pos<4000?3:4;
    int tdx = sel[img*KTOT+pos];
    float logit = obj[(size_t)img*TT+tdx];
    const float* a=anc+4*(size_t)tdx;
    const float* d=del+((size_t)img*TT+tdx)*4;
    float w=a[2]-a[0], h=a[3]-a[1];
    float cx=a[0]+0.5f*w, cy=a[1]+0.5f*h;
    float dw=fminf(d[2],BCLIP), dh=fminf(d[3],BCLIP);
    float pcx=d[0]*w+cx, pcy=d[1]*h+cy;
    float pw=expf(dw)*w, ph=expf(dh)*h;
    float x1=pcx-0.5f*pw, y1=pcy-0.5f*ph;
    float x2=pcx+0.5f*pw, y2=pcy+0.5f*ph;
    x1=fminf(fmaxf(x1,0.f),800.f); y1=fminf(fmaxf(y1,0.f),800.f);
    x2=fminf(fmaxf(x2,0.f),800.f); y2=fminf(fmaxf(y2,0.f),800.f);
    int valid=(x2-x1>=1e-3f)&&(y2-y1>=1e-3f);
    float sc=1.f/(1.f+expf(-logit));
    float sv=valid? sc : -INFINITY;
    gkey[img*KTOT+pos]=((unsigned long long)fkey(sv)<<32)|(unsigned)(KTOT-1-pos);
    float* pb=pbox+((size_t)img*KTOT+pos)*4;
    pb[0]=x1; pb[1]=y1; pb[2]=x2; pb[3]=y2;
    pscore[img*KTOT+pos]=sc;
    plvl[img*KTOT+pos]=lvl|(valid?0:256);
    lm=fmaxf(fmaxf(x1,y1),fmaxf(x2,y2));
  }
  smax[threadIdx.x]=lm; __syncthreads();
  for(int st=128;st>0;st>>=1){
    if(threadIdx.x<st) smax[threadIdx.x]=fmaxf(smax[threadIdx.x],smax[threadIdx.x+st]);
    __syncthreads();
  }
  // coords >= 0, so u32 compare == float compare; max over all blocks is exact
  if(threadIdx.x==0) atomicMax(&gmaxu[img], __float_as_uint(smax[0]));
}

// ---------------- K2b: partial rank counts, 256x256 tiles ---------------------
__global__ __launch_bounds__(256) void k_rankp(const unsigned long long* __restrict__ gkey,
    int* __restrict__ grank){
  const int img=blockIdx.x, ic=blockIdx.y, jc=blockIdx.z;
  __shared__ unsigned long long sk[256];
  const int jbase=jc*256;
  const int jend=min(256, KTOT-jbase);
  const int i=ic*256+threadIdx.x;
  if(threadIdx.x<jend) sk[threadIdx.x]=gkey[img*KTOT+jbase+threadIdx.x];
  __syncthreads();
  if(i>=KTOT) return;
  const unsigned long long mk=gkey[img*KTOT+i];
  int r=0;
  #pragma unroll 4
  for(int j=0;j<jend;j++) r+=(sk[j]>mk)?1:0;
  if(r) atomicAdd(&grank[img*KTOT+i], r);
}

// ---------------- K2c: scatter by rank ---------------------------------------
__global__ __launch_bounds__(256) void k_scatter(const int* __restrict__ grank,
    const float4* __restrict__ pbox, const float* __restrict__ pscore,
    const int* __restrict__ plvl,
    float4* __restrict__ sbox, float* __restrict__ sscore,
    int* __restrict__ slvl, int* __restrict__ ssupp){
  const int img=blockIdx.x/18, chunk=blockIdx.x%18;
  const int pos=chunk*256+threadIdx.x;
  if(pos>=KTOT) return;
  const int rank=grank[img*KTOT+pos];
  sbox[(size_t)img*KTOT+rank]=pbox[(size_t)img*KTOT+pos];
  sscore[img*KTOT+rank]=pscore[img*KTOT+pos];
  int lv=plvl[img*KTOT+pos];
  slvl[img*KTOT+rank]=lv&0xFF;
  ssupp[img*KTOT+rank]=(lv>>8)&1;   // invalid -> pre-suppressed
}

// ---------------- K3a: candidate list; LDS-staged predicate, wave-0 ballot ----
__global__ __launch_bounds__(256) void k_list(const float* __restrict__ sbox,
    const int* __restrict__ slvl, const int* __restrict__ ssupp,
    const unsigned* __restrict__ gmaxu,
    int* __restrict__ lists, int* __restrict__ mcnt,
    float4* __restrict__ nbox, float* __restrict__ narea){
  const int img=blockIdx.x/5, lvl=blockIdx.x%5;
  const int tid=threadIdx.x;
  __shared__ unsigned char s_ok[KTOT];
  __shared__ int s_list[1024];
  __shared__ int s_m;
  for(int i=tid;i<KTOT;i+=256)
    s_ok[i]=(slvl[img*KTOT+i]==lvl && ssupp[img*KTOT+i]==0)?1:0;
  __syncthreads();
  if(tid<64){
    int base=0;
    for(int t=0;t<KTOT;t+=64){
      int r=t+tid;
      bool pred=(r<KTOT) && s_ok[r];
      unsigned long long b=__ballot(pred);
      int pre=__popcll(b & ((1ull<<tid)-1ull));
      if(pred) s_list[base+pre]=r;
      base+=__popcll(b);
    }
    if(tid==0){ s_m=base; mcnt[blockIdx.x]=base; }
  }
  __syncthreads();
  const int m=s_m;
  const float off=(float)lvl*(__uint_as_float(gmaxu[img])+1.0f);  // ref offset math
  const float4* sb4=(const float4*)sbox;
  for(int i=tid;i<m;i+=256){
    int r=s_list[i];
    lists[blockIdx.x*1024+i]=r;
    float4 bx=sb4[(size_t)img*KTOT+r];
    float a0=bx.x+off, a1=bx.y+off, a2=bx.z+off, a3=bx.w+off;
    nbox[blockIdx.x*1024+i]=make_float4(a0,a1,a2,a3);
    narea[blockIdx.x*1024+i]=(a2-a0)*(a3-a1);
  }
}

// ---------------- K3b: pairwise suppression bitmasks, 1 word/thread ------------
__global__ __launch_bounds__(256) void k_mask(const float4* __restrict__ nbox,
    const float* __restrict__ narea, const int* __restrict__ mcnt,
    unsigned long long* __restrict__ mask){
  const int il=blockIdx.x;
  const int rc=blockIdx.y>>4, w=blockIdx.y&15;
  const int m=mcnt[il];
  const int r0=rc*256;
  if(r0>=m) return;
  const int i=r0+threadIdx.x;
  const int wlast=(m+63)>>6;
  __shared__ float4 sb[64];
  __shared__ float  sa[64];
  unsigned long long bits=0ull;
  const bool block_active = (w>=rc*4) && (w<wlast);   // rc*4 == min wi in block
  if(block_active){
    const int jend=min(64, m-w*64);
    if(threadIdx.x<64 && threadIdx.x<jend){
      sb[threadIdx.x]=nbox[il*1024+w*64+threadIdx.x];
      sa[threadIdx.x]=narea[il*1024+w*64+threadIdx.x];
    }
    __syncthreads();
    const int wi=i>>6;
    if(i<m && w>=wi){
      const float4 bi=nbox[il*1024+i];
      const float  ai=narea[il*1024+i];
      for(int jj=0;jj<jend;++jj){
        const float4 bj=sb[jj];                 // LDS broadcast
        float ltx=fmaxf(bi.x,bj.x), lty=fmaxf(bi.y,bj.y);
        float rbx=fminf(bi.z,bj.z), rby=fminf(bi.w,bj.w);
        float wx=fmaxf(rbx-ltx,0.f), wy=fmaxf(rby-lty,0.f);
        float inter=wx*wy;
        float iou=inter/((ai+sa[jj])-inter);
        bits |= (iou>0.7f)? (1ull<<jj) : 0ull;
      }
      if(w==wi){ int b=i&63; bits &= ~((2ull<<b)-1ull); }  // keep only j>i
    }
  }
  if(i<m) mask[((size_t)il*1024+i)*16+w]=bits;
}

// ---------------- K3c: greedy reduce; unconditional ds_reads (padded rows) ----
__global__ __launch_bounds__(256) void k_reduce(const unsigned long long* __restrict__ mask,
    const int* __restrict__ mcnt, const int* __restrict__ lists,
    int* __restrict__ ssupp){
  const int il=blockIdx.x, img=il/5;
  const int m=mcnt[il];
  const int m_pad=(m+15)&~15;
  __shared__ unsigned long long smask[1024*16];   // 128 KB slab
  // cooperative global->LDS copy, 8 loads in flight per thread, no tail loop
  {
    const float4* g4=(const float4*)(mask + (size_t)il*1024*16);
    float4* l4=(float4*)smask;
    const int tot4=(m*8+2047)&~2047;              // <= 8192 always (m<=1000)
    for(int i=threadIdx.x;i<tot4;i+=2048){
      float4 r0=g4[i      ], r1=g4[i+ 256], r2=g4[i+ 512], r3=g4[i+ 768];
      float4 r4=g4[i+1024], r5=g4[i+1280], r6=g4[i+1536], r7=g4[i+1792];
      l4[i      ]=r0; l4[i+ 256]=r1; l4[i+ 512]=r2; l4[i+ 768]=r3;
      l4[i+1024]=r4; l4[i+1280]=r5; l4[i+1536]=r6; l4[i+1792]=r7;
    }
  }
  __syncthreads();
  // zero-pad rows [m, m_pad) so the walk needs no bounds checks
  if(threadIdx.x<(m_pad-m)*16) smask[(unsigned)m*16+threadIdx.x]=0ull;
  __syncthreads();
  if(threadIdx.x>=64) return;
  const int lane=threadIdx.x;
  const int seg=lane&15;      // lanes 16+ mirror lanes 0-15 (LDS broadcast, free)
  unsigned long long remv=0ull;
  unsigned long long c0,c1,c2,c3,c4,c5,c6,c7,c8,c9,c10,c11,c12,c13,c14,c15;
  unsigned long long n0,n1,n2,n3,n4,n5,n6,n7,n8,n9,n10,n11,n12,n13,n14,n15;
#define LD(r,b) smask[(unsigned)((b)+(r))*16+seg]
  c0 =LD(0,0);  c1 =LD(1,0);  c2 =LD(2,0);  c3 =LD(3,0);
  c4 =LD(4,0);  c5 =LD(5,0);  c6 =LD(6,0);  c7 =LD(7,0);
  c8 =LD(8,0);  c9 =LD(9,0);  c10=LD(10,0); c11=LD(11,0);
  c12=LD(12,0); c13=LD(13,0); c14=LD(14,0); c15=LD(15,0);
  for(int g=0;;++g){
    const int nb=(g+1)*16;
    n0 =LD(0,nb);  n1 =LD(1,nb);  n2 =LD(2,nb);  n3 =LD(3,nb);
    n4 =LD(4,nb);  n5 =LD(5,nb);  n6 =LD(6,nb);  n7 =LD(7,nb);
    n8 =LD(8,nb);  n9 =LD(9,nb);  n10=LD(10,nb); n11=LD(11,nb);
    n12=LD(12,nb); n13=LD(13,nb); n14=LD(14,nb); n15=LD(15,nb);
    // lane-local simulated decisions; lane w authoritative (base%64 in {0,16,32,48})
    const int base=g*16;
    const int w=base>>6;          // wave-uniform, < 16
    const int bb=base&63;
    unsigned t8=(unsigned)(remv>>bb);
    unsigned am=0u;
#define DEC(r,cr) { unsigned alive=1u^((t8>>(r))&1u); am|=alive<<(r); \
                    if(alive) t8|=(unsigned)((cr)>>bb); }
    DEC(0,c0)  DEC(1,c1)  DEC(2,c2)  DEC(3,c3)
    DEC(4,c4)  DEC(5,c5)  DEC(6,c6)  DEC(7,c7)
    DEC(8,c8)  DEC(9,c9)  DEC(10,c10) DEC(11,c11)
    DEC(12,c12) DEC(13,c13) DEC(14,c14) DEC(15,c15)
#undef DEC
    unsigned am_w=__builtin_amdgcn_readlane(am, w);   // SALU path, no LDS op
#define APP(r,cr) { unsigned long long mk64=0ull-(unsigned long long)((am_w>>(r))&1u); \
                    remv|=(cr)&mk64; }
    APP(0,c0)  APP(1,c1)  APP(2,c2)  APP(3,c3)
    APP(4,c4)  APP(5,c5)  APP(6,c6)  APP(7,c7)
    APP(8,c8)  APP(9,c9)  APP(10,c10) APP(11,c11)
    APP(12,c12) APP(13,c13) APP(14,c14) APP(15,c15)
#undef APP
    if(nb>=m) break;
    c0 =n0;  c1 =n1;  c2 =n2;  c3 =n3;  c4 =n4;  c5 =n5;  c6 =n6;  c7 =n7;
    c8 =n8;  c9 =n9;  c10=n10; c11=n11; c12=n12; c13=n13; c14=n14; c15=n15;
  }
#undef LD
  const int* list = lists + il*1024;
  for(int t=0;t<m;t+=64){
    int i=t+lane;
    unsigned long long word=__shfl(remv, (i<m? i:0)>>6);
    if(i<m && ((word>>(i&63))&1ull)) ssupp[img*KTOT+list[i]]=1;
  }
}

// ---------------- K4: compact survivors; LDS-staged predicate -----------------
__global__ __launch_bounds__(256) void k_out(const float* __restrict__ sbox,
    const float* __restrict__ sscore, const int* __restrict__ ssupp,
    float* __restrict__ out){
  const int img=blockIdx.x;
  const int tid=threadIdx.x;
  __shared__ unsigned char s_ok[KTOT];
  __shared__ unsigned short list[POST];
  __shared__ int s_c;
  for(int i=tid;i<KTOT;i+=256) s_ok[i]=(ssupp[img*KTOT+i]==0)?1:0;
  __syncthreads();
  if(tid<64){
    int base=0;
    for(int t=0;t<KTOT && base<POST;t+=64){
      int r=t+tid;
      bool pred=(r<KTOT) && s_ok[r];
      unsigned long long b=__ballot(pred);
      int pre=__popcll(b & ((1ull<<tid)-1ull));
      if(pred && base+pre<POST) list[base+pre]=(unsigned short)r;
      base+=__popcll(b);
    }
    if(tid==0) s_c=min(base,POST);
  }
  __syncthreads();
  const int c=s_c;
  for(int o=tid;o<POST;o+=256){
    float* row=out+((size_t)img*POST+o)*5;
    if(o<c){
      int r=list[o];
      const float* b=sbox+((size_t)img*KTOT+r)*4;
      row[0]=b[0]; row[1]=b[1]; row[2]=b[2]; row[3]=b[3];
      row[4]=sscore[img*KTOT+r];
    } else {
      row[0]=0.f; row[1]=0.f; row[2]=0.f; row[3]=0.f; row[4]=0.f;
    }
  }
}

extern "C" void kernel_launch(void* const* d_in, const int* in_sizes, int n_in,
                              void* d_out, int out_size, void* d_ws, size_t ws_size,
                              hipStream_t stream){
  const float* obj=(const float*)d_in[0];
  const float* del=(const float*)d_in[1];
  const float* anc=(const float*)d_in[2];
  float* out=(float*)d_out;

  char* w=(char*)d_ws;
  size_t off=0;
  auto alloc=[&](size_t bytes)->void*{
    void* p=w+off; off+=(bytes+255)&~(size_t)255; return p;
  };
  int*  sel    =(int*)  alloc(sizeof(int)*NIMG*KTOT);
  int*  sel2   =(int*)  alloc(sizeof(int)*NIMG*KTOT);
  float* pbox  =(float*)alloc(sizeof(float)*NIMG*KTOT*4);
  float* pscore=(float*)alloc(sizeof(float)*NIMG*KTOT);
  int*  plvl   =(int*)  alloc(sizeof(int)*NIMG*KTOT);
  unsigned long long* gkey=(unsigned long long*)alloc(sizeof(unsigned long long)*NIMG*KTOT);
  float* sbox  =(float*)alloc(sizeof(float)*NIMG*KTOT*4);
  float* sscore=(float*)alloc(sizeof(float)*NIMG*KTOT);
  int*  slvl   =(int*)  alloc(sizeof(int)*NIMG*KTOT);
  int*  ssupp  =(int*)  alloc(sizeof(int)*NIMG*KTOT);
  unsigned* gmaxu=(unsigned*)alloc(sizeof(unsigned)*NIMG);
  int*  eqbuf  =(int*)  alloc(sizeof(int)*40*2048);
  int*  lists  =(int*)  alloc(sizeof(int)*40*1024);
  int*  mcnt   =(int*)  alloc(sizeof(int)*40);
  float4* nbox =(float4*)alloc(sizeof(float4)*40*1024);
  float* narea =(float*)alloc(sizeof(float)*40*1024);
  unsigned long long* mask=(unsigned long long*)alloc(sizeof(unsigned long long)*40*1024*16);
  unsigned* ghist=(unsigned*)alloc(sizeof(unsigned)*40*2048);
  unsigned* gpref=(unsigned*)alloc(sizeof(unsigned)*40);
  int*  gkrem  =(int*)  alloc(sizeof(int)*40);
  int*  gcnt   =(int*)  alloc(sizeof(int)*80);
  int*  grank  =(int*)  alloc(sizeof(int)*NIMG*KTOT);

  hipLaunchKernelGGL(k_zero,    dim3((40*2048+NIMG*KTOT+NIMG+255)/256), dim3(256), 0, stream,
                     ghist, grank, gmaxu);
  hipLaunchKernelGGL(k_hist<0>, dim3(40,NSUB), dim3(256), 0, stream, obj, gpref, ghist);
  hipLaunchKernelGGL(k_scan<0>, dim3(40), dim3(256), 0, stream, ghist, gpref, gkrem, gcnt);
  hipLaunchKernelGGL(k_hist<1>, dim3(40,NSUB), dim3(256), 0, stream, obj, gpref, ghist);
  hipLaunchKernelGGL(k_scan<1>, dim3(40), dim3(256), 0, stream, ghist, gpref, gkrem, gcnt);
  hipLaunchKernelGGL(k_hist<2>, dim3(40,NSUB), dim3(256), 0, stream, obj, gpref, ghist);
  hipLaunchKernelGGL(k_scan<2>, dim3(40), dim3(256), 0, stream, ghist, gpref, gkrem, gcnt);
  hipLaunchKernelGGL(k_sel,    dim3(40,NSUB), dim3(256), 0, stream, obj, gpref, gkrem,
                     gcnt, sel, eqbuf);
  hipLaunchKernelGGL(k_sortd,  dim3(40,4), dim3(256), 0, stream, obj, gkrem, gcnt,
                     sel, sel2, eqbuf);
  hipLaunchKernelGGL(k_decode, dim3(NIMG*18), dim3(256), 0, stream, obj, del, anc, sel2,
                     pbox, pscore, plvl, gkey, gmaxu);
  hipLaunchKernelGGL(k_rankp,  dim3(NIMG,18,18), dim3(256), 0, stream, gkey, grank);
  hipLaunchKernelGGL(k_scatter,dim3(NIMG*18), dim3(256), 0, stream, grank,
                     (const float4*)pbox, pscore, plvl,
                     (float4*)sbox, sscore, slvl, ssupp);
  hipLaunchKernelGGL(k_list,   dim3(40), dim3(256), 0, stream, sbox, slvl, ssupp, gmaxu,
                     lists, mcnt, nbox, narea);
  hipLaunchKernelGGL(k_mask,   dim3(40,64), dim3(256), 0, stream, nbox, narea, mcnt, mask);
  hipLaunchKernelGGL(k_reduce, dim3(40), dim3(256), 0, stream, mask, mcnt, lists, ssupp);
  hipLaunchKernelGGL(k_out,    dim3(NIMG), dim3(256), 0, stream, sbox, sscore, ssupp, out);
}

// Round 13
// 151.849 us; speedup vs baseline: 1.9290x; 1.0578x over previous
//
#include <hip/hip_runtime.h>
#include <math.h>

#define NIMG 8
#define TT   159882
#define KTOT 4507
#define POST 1000
#define NSUB 32

__constant__ int c_n[5]   = {120000,30000,7500,1875,507};
__constant__ int c_off[5] = {0,120000,150000,157500,159375};
__constant__ int c_k[5]   = {1000,1000,1000,1000,507};
__constant__ int c_pos[5] = {0,1000,2000,3000,4000};

__device__ __forceinline__ unsigned fkey(float f){
  unsigned u=__float_as_uint(f);
  return (u&0x80000000u)? ~u : (u|0x80000000u);
}

// ---------------- K0: zero global histograms + rank array + gmax --------------
__global__ __launch_bounds__(256) void k_zero(unsigned* __restrict__ ghist,
                                              int* __restrict__ grank,
                                              unsigned* __restrict__ gmaxu){
  int i=blockIdx.x*256+threadIdx.x;
  if(i<40*2048) ghist[i]=0u;
  int j=i-40*2048;
  if(j>=0 && j<NIMG*KTOT) grank[j]=0;
  int j2=j-NIMG*KTOT;
  if(j2>=0 && j2<NIMG) gmaxu[j2]=0u;
}

// ---------------- K1a: distributed radix histogram (2 rounds of 11 bits) ------
template<int RND>
__global__ __launch_bounds__(256) void k_hist(const float* __restrict__ obj,
    const unsigned* __restrict__ gpref, unsigned* __restrict__ ghist){
  constexpr int sh=(RND==0)?21:10;
  constexpr unsigned msk=2047u;
  const int il=blockIdx.x, sub=blockIdx.y;
  const int img=il/5, lvl=il%5;
  const int n=c_n[lvl], k=c_k[lvl];
  if(k>=n) return;
  const int chunk=(n+NSUB-1)/NSUB;
  const int start=sub*chunk, end=min(start+chunk,n);
  if(start>=end) return;
  const float* o=obj+(size_t)img*TT+c_off[lvl];
  __shared__ unsigned hist[2048];
  const unsigned prefix=(RND==0)?0u:gpref[il];
  for(int i=threadIdx.x;i<2048;i+=256) hist[i]=0u;
  __syncthreads();
  for(int i=start+threadIdx.x;i<end;i+=256){
    unsigned key=fkey(o[i]);
    if(RND==0){
      atomicAdd(&hist[(key>>sh)&msk],1u);
    } else {
      if((key&0xFFE00000u)==prefix) atomicAdd(&hist[(key>>sh)&msk],1u);
    }
  }
  __syncthreads();
  for(int b=threadIdx.x;b<2048;b+=256){
    unsigned v=hist[b];
    if(v) atomicAdd(&ghist[il*2048+b],v);
  }
}

// ---------------- K1b: pick bucket via register suffix-sum + LDS tree ---------
template<int RND>
__global__ __launch_bounds__(256) void k_scan(unsigned* __restrict__ ghist,
    unsigned* __restrict__ gpref, int* __restrict__ gkrem,
    int* __restrict__ gcnt){
  constexpr int sh=(RND==0)?21:10;
  constexpr int C=8;   // 2048/256
  const int il=blockIdx.x, lvl=il%5;
  const int n=c_n[lvl], k=c_k[lvl];
  const int t=threadIdx.x;
  __shared__ unsigned tot[256];
  if(k>=n){
    if(RND==1 && t==0){ gpref[il]=0u; gkrem[il]=0; gcnt[il*2]=0; gcnt[il*2+1]=0; }
    return;
  }
  const int kr=(RND==0)?k:gkrem[il];
  unsigned v[C];
#pragma unroll
  for(int i=0;i<C;i++) v[i]=ghist[il*2048+t*C+i];
#pragma unroll
  for(int i=C-2;i>=0;i--) v[i]+=v[i+1];          // local suffix sum (registers)
  tot[t]=v[0];
  __syncthreads();
#pragma unroll
  for(int d=1;d<256;d<<=1){                       // inclusive suffix scan of totals
    unsigned add=(t+d<256)?tot[t+d]:0u;
    __syncthreads();
    tot[t]+=add;
    __syncthreads();
  }
  unsigned tail=(t<255)?tot[t+1]:0u;
#pragma unroll
  for(int i=0;i<C;i++){
    unsigned suf=v[i]+tail;
    unsigned sufn=((i<C-1)?v[i+1]:0u)+tail;
    if(suf>=(unsigned)kr && sufn<(unsigned)kr){
      unsigned prevPref=(RND==0)?0u:gpref[il];
      gpref[il]=prevPref|((unsigned)(t*C+i)<<sh);
      gkrem[il]=kr-(int)sufn;
    }
  }
  for(int b=t;b<2048;b+=256) ghist[il*2048+b]=0u; // ready for next round/replay
  if(RND==1 && t==0){ gcnt[il*2]=0; gcnt[il*2+1]=0; }
}

// ---------------- K1c: selection vs 22-bit masked threshold; LDS aggregation --
// gt: masked key above the bucket (count == k - krem by radix construction).
// eq: bucket members (tiny after 22 bits); k_sortd picks top krem by
// (full key desc, idx asc) == reference lax.top_k tie-break.
__global__ __launch_bounds__(256) void k_sel(const float* __restrict__ obj,
    const unsigned* __restrict__ gpref, const int* __restrict__ gkrem,
    int* __restrict__ gcnt, int* __restrict__ sel, int* __restrict__ eqbuf){
  const int il=blockIdx.x, sub=blockIdx.y;
  const int img=il/5, lvl=il%5;
  const int n=c_n[lvl], k=c_k[lvl];
  const int chunk=(n+NSUB-1)/NSUB;
  const int start=sub*chunk, end=min(start+chunk,n);
  if(start>=end) return;
  int* s=sel+img*KTOT+c_pos[lvl];
  if(k>=n){
    for(int i=start+threadIdx.x;i<end;i+=256) s[i]=i;
    return;
  }
  __shared__ int s_gt[1024];     // block share of gt-list (total cgt <= 1000)
  __shared__ int s_eq[2048];
  __shared__ int cnt_gt, cnt_eq, base_gt, base_eq;
  if(threadIdx.x==0){ cnt_gt=0; cnt_eq=0; }
  __syncthreads();
  const float* o=obj+(size_t)img*TT+c_off[lvl];
  const unsigned t=gpref[il];           // bits 10..31 of threshold, low 10 zero
  const int krem=gkrem[il];
  for(int i=start+threadIdx.x;i<end;i+=256){
    unsigned mk=fkey(o[i])&0xFFFFFC00u;
    if(mk>t){ int p=atomicAdd(&cnt_gt,1); s_gt[p]=i; }
    else if(mk==t && krem>0){ int p=atomicAdd(&cnt_eq,1); if(p<2048) s_eq[p]=i; }
  }
  __syncthreads();
  const int cg=cnt_gt, ce=min(cnt_eq,2048);
  if(threadIdx.x==0) base_gt=(cg>0)? atomicAdd(&gcnt[il*2],cg) : 0;
  if(threadIdx.x==1) base_eq=(ce>0)? atomicAdd(&gcnt[il*2+1],ce) : 0;
  __syncthreads();
  for(int i=threadIdx.x;i<cg;i+=256) s[base_gt+i]=s_gt[i];
  for(int i=threadIdx.x;i<ce;i+=256){
    int p=base_eq+i;
    if(p<2048) eqbuf[il*2048+p]=s_eq[i];
  }
}

// ---------------- K1d: distributed level rank-sort -> sel2 --------------------
__global__ __launch_bounds__(256) void k_sortd(const float* __restrict__ obj,
    const int* __restrict__ gkrem, const int* __restrict__ gcnt,
    const int* __restrict__ sel, int* __restrict__ sel2,
    const int* __restrict__ eqbuf){
  const int il=blockIdx.x, chunk=blockIdx.y;
  const int img=il/5, lvl=il%5;
  const int n=c_n[lvl], k=c_k[lvl];
  if(chunk*256>=k) return;
  const float* o=obj+(size_t)img*TT+c_off[lvl];
  const int* s=sel+img*KTOT+c_pos[lvl];
  int* s2=sel2+img*KTOT+c_pos[lvl];
  __shared__ unsigned long long skey[1024];
  __shared__ unsigned long long eqk[2048];
  int cgt, krem;
  if(k<n){ cgt=gcnt[il*2]; krem=gkrem[il]; } else { cgt=k; krem=0; }
  const int ceq = (krem>0)? min(gcnt[il*2+1],2048) : 0;
  for(int i=threadIdx.x;i<cgt;i+=256){
    int idx=s[i];
    skey[i]=((unsigned long long)fkey(o[idx])<<32)|(unsigned)(~(unsigned)idx);
  }
  for(int i=threadIdx.x;i<ceq;i+=256){
    int idx=eqbuf[il*2048+i];
    eqk[i]=((unsigned long long)fkey(o[idx])<<32)|(unsigned)(~(unsigned)idx);
  }
  __syncthreads();
  if(krem>0 && threadIdx.x==0){
    for(int r2=0;r2<krem;r2++){        // pick max key64 = (key desc, idx asc)
      unsigned long long best=0ull; int bi=0;
      for(int j=0;j<ceq;j++){ unsigned long long kk=eqk[j]; if(kk>best){best=kk;bi=j;} }
      skey[cgt+r2]=best; eqk[bi]=0ull;
    }
  }
  __syncthreads();
  const int i=chunk*256+threadIdx.x;
  if(i>=k) return;
  const unsigned long long mk=skey[i];
  int rank=0, j=0;
  const int k8=k&~7;
  for(;j<k8;j+=8){
    unsigned long long a0=skey[j  ],a1=skey[j+1],a2=skey[j+2],a3=skey[j+3];
    unsigned long long a4=skey[j+4],a5=skey[j+5],a6=skey[j+6],a7=skey[j+7];
    rank+=((a0>mk)?1:0)+((a1>mk)?1:0)+((a2>mk)?1:0)+((a3>mk)?1:0)
         +((a4>mk)?1:0)+((a5>mk)?1:0)+((a6>mk)?1:0)+((a7>mk)?1:0);
  }
  for(;j<k;j++) rank+=(skey[j]>mk)?1:0;
  int idx=(int)(~(unsigned)(mk&0xFFFFFFFFu));
  s2[rank]=idx+c_off[lvl];
}

// ---------------- K2a: decode+clip+score; 144 blocks, atomicMax image max -----
__global__ __launch_bounds__(256) void k_decode(const float* __restrict__ obj,
    const float* __restrict__ del, const float* __restrict__ anc,
    const int* __restrict__ sel, float* __restrict__ pbox, float* __restrict__ pscore,
    int* __restrict__ plvl, unsigned long long* __restrict__ gkey,
    unsigned* __restrict__ gmaxu){
  const int img=blockIdx.x/18, chunk=blockIdx.x%18;
  const int pos=chunk*256+threadIdx.x;
  __shared__ float smax[256];
  const float BCLIP=(float)4.135166556742356;  // log(1000/16)
  float lm=0.f;
  if(pos<KTOT){
    int lvl = pos<1000?0:pos<2000?1:pos<3000?2:pos<4000?3:4;
    int tdx = sel[img*KTOT+pos];
    float logit = obj[(size_t)img*TT+tdx];
    const float* a=anc+4*(size_t)tdx;
    const float* d=del+((size_t)img*TT+tdx)*4;
    float w=a[2]-a[0], h=a[3]-a[1];
    float cx=a[0]+0.5f*w, cy=a[1]+0.5f*h;
    float dw=fminf(d[2],BCLIP), dh=fminf(d[3],BCLIP);
    float pcx=d[0]*w+cx, pcy=d[1]*h+cy;
    float pw=expf(dw)*w, ph=expf(dh)*h;
    float x1=pcx-0.5f*pw, y1=pcy-0.5f*ph;
    float x2=pcx+0.5f*pw, y2=pcy+0.5f*ph;
    x1=fminf(fmaxf(x1,0.f),800.f); y1=fminf(fmaxf(y1,0.f),800.f);
    x2=fminf(fmaxf(x2,0.f),800.f); y2=fminf(fmaxf(y2,0.f),800.f);
    int valid=(x2-x1>=1e-3f)&&(y2-y1>=1e-3f);
    float sc=1.f/(1.f+expf(-logit));
    float sv=valid? sc : -INFINITY;
    gkey[img*KTOT+pos]=((unsigned long long)fkey(sv)<<32)|(unsigned)(KTOT-1-pos);
    float* pb=pbox+((size_t)img*KTOT+pos)*4;
    pb[0]=x1; pb[1]=y1; pb[2]=x2; pb[3]=y2;
    pscore[img*KTOT+pos]=sc;
    plvl[img*KTOT+pos]=lvl|(valid?0:256);
    lm=fmaxf(fmaxf(x1,y1),fmaxf(x2,y2));
  }
  smax[threadIdx.x]=lm; __syncthreads();
  for(int st=128;st>0;st>>=1){
    if(threadIdx.x<st) smax[threadIdx.x]=fmaxf(smax[threadIdx.x],smax[threadIdx.x+st]);
    __syncthreads();
  }
  // coords >= 0, so u32 compare == float compare; max over all blocks is exact
  if(threadIdx.x==0) atomicMax(&gmaxu[img], __float_as_uint(smax[0]));
}

// ---------------- K2b: partial rank counts, 256x256 tiles ---------------------
__global__ __launch_bounds__(256) void k_rankp(const unsigned long long* __restrict__ gkey,
    int* __restrict__ grank){
  const int img=blockIdx.x, ic=blockIdx.y, jc=blockIdx.z;
  __shared__ unsigned long long sk[256];
  const int jbase=jc*256;
  const int jend=min(256, KTOT-jbase);
  const int i=ic*256+threadIdx.x;
  if(threadIdx.x<jend) sk[threadIdx.x]=gkey[img*KTOT+jbase+threadIdx.x];
  __syncthreads();
  if(i>=KTOT) return;
  const unsigned long long mk=gkey[img*KTOT+i];
  int r=0;
  #pragma unroll 4
  for(int j=0;j<jend;j++) r+=(sk[j]>mk)?1:0;
  if(r) atomicAdd(&grank[img*KTOT+i], r);
}

// ---------------- K2c: scatter by rank ---------------------------------------
__global__ __launch_bounds__(256) void k_scatter(const int* __restrict__ grank,
    const float4* __restrict__ pbox, const float* __restrict__ pscore,
    const int* __restrict__ plvl,
    float4* __restrict__ sbox, float* __restrict__ sscore,
    int* __restrict__ slvl, int* __restrict__ ssupp){
  const int img=blockIdx.x/18, chunk=blockIdx.x%18;
  const int pos=chunk*256+threadIdx.x;
  if(pos>=KTOT) return;
  const int rank=grank[img*KTOT+pos];
  sbox[(size_t)img*KTOT+rank]=pbox[(size_t)img*KTOT+pos];
  sscore[img*KTOT+rank]=pscore[img*KTOT+pos];
  int lv=plvl[img*KTOT+pos];
  slvl[img*KTOT+rank]=lv&0xFF;
  ssupp[img*KTOT+rank]=(lv>>8)&1;   // invalid -> pre-suppressed
}

// ---------------- K3a: candidate list; LDS-staged predicate, wave-0 ballot ----
__global__ __launch_bounds__(256) void k_list(const float* __restrict__ sbox,
    const int* __restrict__ slvl, const int* __restrict__ ssupp,
    const unsigned* __restrict__ gmaxu,
    int* __restrict__ lists, int* __restrict__ mcnt,
    float4* __restrict__ nbox, float* __restrict__ narea){
  const int img=blockIdx.x/5, lvl=blockIdx.x%5;
  const int tid=threadIdx.x;
  __shared__ unsigned char s_ok[KTOT];
  __shared__ int s_list[1024];
  __shared__ int s_m;
  for(int i=tid;i<KTOT;i+=256)
    s_ok[i]=(slvl[img*KTOT+i]==lvl && ssupp[img*KTOT+i]==0)?1:0;
  __syncthreads();
  if(tid<64){
    int base=0;
    for(int t=0;t<KTOT;t+=64){
      int r=t+tid;
      bool pred=(r<KTOT) && s_ok[r];
      unsigned long long b=__ballot(pred);
      int pre=__popcll(b & ((1ull<<tid)-1ull));
      if(pred) s_list[base+pre]=r;
      base+=__popcll(b);
    }
    if(tid==0){ s_m=base; mcnt[blockIdx.x]=base; }
  }
  __syncthreads();
  const int m=s_m;
  const float off=(float)lvl*(__uint_as_float(gmaxu[img])+1.0f);  // ref offset math
  const float4* sb4=(const float4*)sbox;
  for(int i=tid;i<m;i+=256){
    int r=s_list[i];
    lists[blockIdx.x*1024+i]=r;
    float4 bx=sb4[(size_t)img*KTOT+r];
    float a0=bx.x+off, a1=bx.y+off, a2=bx.z+off, a3=bx.w+off;
    nbox[blockIdx.x*1024+i]=make_float4(a0,a1,a2,a3);
    narea[blockIdx.x*1024+i]=(a2-a0)*(a3-a1);
  }
}

// ---------------- K3b: pairwise suppression bitmasks, 1 word/thread ------------
__global__ __launch_bounds__(256) void k_mask(const float4* __restrict__ nbox,
    const float* __restrict__ narea, const int* __restrict__ mcnt,
    unsigned long long* __restrict__ mask){
  const int il=blockIdx.x;
  const int rc=blockIdx.y>>4, w=blockIdx.y&15;
  const int m=mcnt[il];
  const int r0=rc*256;
  if(r0>=m) return;
  const int i=r0+threadIdx.x;
  const int wlast=(m+63)>>6;
  __shared__ float4 sb[64];
  __shared__ float  sa[64];
  unsigned long long bits=0ull;
  const bool block_active = (w>=rc*4) && (w<wlast);   // rc*4 == min wi in block
  if(block_active){
    const int jend=min(64, m-w*64);
    if(threadIdx.x<64 && threadIdx.x<jend){
      sb[threadIdx.x]=nbox[il*1024+w*64+threadIdx.x];
      sa[threadIdx.x]=narea[il*1024+w*64+threadIdx.x];
    }
    __syncthreads();
    const int wi=i>>6;
    if(i<m && w>=wi){
      const float4 bi=nbox[il*1024+i];
      const float  ai=narea[il*1024+i];
      for(int jj=0;jj<jend;++jj){
        const float4 bj=sb[jj];                 // LDS broadcast
        float ltx=fmaxf(bi.x,bj.x), lty=fmaxf(bi.y,bj.y);
        float rbx=fminf(bi.z,bj.z), rby=fminf(bi.w,bj.w);
        float wx=fmaxf(rbx-ltx,0.f), wy=fmaxf(rby-lty,0.f);
        float inter=wx*wy;
        float iou=inter/((ai+sa[jj])-inter);
        bits |= (iou>0.7f)? (1ull<<jj) : 0ull;
      }
      if(w==wi){ int b=i&63; bits &= ~((2ull<<b)-1ull); }  // keep only j>i
    }
  }
  if(i<m) mask[((size_t)il*1024+i)*16+w]=bits;
}

// ---------------- K3c: greedy reduce; unconditional ds_reads (padded rows) ----
__global__ __launch_bounds__(256) void k_reduce(const unsigned long long* __restrict__ mask,
    const int* __restrict__ mcnt, const int* __restrict__ lists,
    int* __restrict__ ssupp){
  const int il=blockIdx.x, img=il/5;
  const int m=mcnt[il];
  const int m_pad=(m+15)&~15;
  __shared__ unsigned long long smask[1024*16];   // 128 KB slab
  // cooperative global->LDS copy, 8 loads in flight per thread, no tail loop
  {
    const float4* g4=(const float4*)(mask + (size_t)il*1024*16);
    float4* l4=(float4*)smask;
    const int tot4=(m*8+2047)&~2047;              // <= 8192 always (m<=1000)
    for(int i=threadIdx.x;i<tot4;i+=2048){
      float4 r0=g4[i      ], r1=g4[i+ 256], r2=g4[i+ 512], r3=g4[i+ 768];
      float4 r4=g4[i+1024], r5=g4[i+1280], r6=g4[i+1536], r7=g4[i+1792];
      l4[i      ]=r0; l4[i+ 256]=r1; l4[i+ 512]=r2; l4[i+ 768]=r3;
      l4[i+1024]=r4; l4[i+1280]=r5; l4[i+1536]=r6; l4[i+1792]=r7;
    }
  }
  __syncthreads();
  // zero-pad rows [m, m_pad) so the walk needs no bounds checks
  if(threadIdx.x<(m_pad-m)*16) smask[(unsigned)m*16+threadIdx.x]=0ull;
  __syncthreads();
  if(threadIdx.x>=64) return;
  const int lane=threadIdx.x;
  const int seg=lane&15;      // lanes 16+ mirror lanes 0-15 (LDS broadcast, free)
  unsigned long long remv=0ull;
  unsigned long long c0,c1,c2,c3,c4,c5,c6,c7,c8,c9,c10,c11,c12,c13,c14,c15;
  unsigned long long n0,n1,n2,n3,n4,n5,n6,n7,n8,n9,n10,n11,n12,n13,n14,n15;
#define LD(r,b) smask[(unsigned)((b)+(r))*16+seg]
  c0 =LD(0,0);  c1 =LD(1,0);  c2 =LD(2,0);  c3 =LD(3,0);
  c4 =LD(4,0);  c5 =LD(5,0);  c6 =LD(6,0);  c7 =LD(7,0);
  c8 =LD(8,0);  c9 =LD(9,0);  c10=LD(10,0); c11=LD(11,0);
  c12=LD(12,0); c13=LD(13,0); c14=LD(14,0); c15=LD(15,0);
  for(int g=0;;++g){
    const int nb=(g+1)*16;
    n0 =LD(0,nb);  n1 =LD(1,nb);  n2 =LD(2,nb);  n3 =LD(3,nb);
    n4 =LD(4,nb);  n5 =LD(5,nb);  n6 =LD(6,nb);  n7 =LD(7,nb);
    n8 =LD(8,nb);  n9 =LD(9,nb);  n10=LD(10,nb); n11=LD(11,nb);
    n12=LD(12,nb); n13=LD(13,nb); n14=LD(14,nb); n15=LD(15,nb);
    // lane-local simulated decisions; lane w authoritative (base%64 in {0,16,32,48})
    const int base=g*16;
    const int w=base>>6;          // wave-uniform, < 16
    const int bb=base&63;
    unsigned t8=(unsigned)(remv>>bb);
    unsigned am=0u;
#define DEC(r,cr) { unsigned alive=1u^((t8>>(r))&1u); am|=alive<<(r); \
                    if(alive) t8|=(unsigned)((cr)>>bb); }
    DEC(0,c0)  DEC(1,c1)  DEC(2,c2)  DEC(3,c3)
    DEC(4,c4)  DEC(5,c5)  DEC(6,c6)  DEC(7,c7)
    DEC(8,c8)  DEC(9,c9)  DEC(10,c10) DEC(11,c11)
    DEC(12,c12) DEC(13,c13) DEC(14,c14) DEC(15,c15)
#undef DEC
    unsigned am_w=__builtin_amdgcn_readlane(am, w);   // SALU path, no LDS op
#define APP(r,cr) { unsigned long long mk64=0ull-(unsigned long long)((am_w>>(r))&1u); \
                    remv|=(cr)&mk64; }
    APP(0,c0)  APP(1,c1)  APP(2,c2)  APP(3,c3)
    APP(4,c4)  APP(5,c5)  APP(6,c6)  APP(7,c7)
    APP(8,c8)  APP(9,c9)  APP(10,c10) APP(11,c11)
    APP(12,c12) APP(13,c13) APP(14,c14) APP(15,c15)
#undef APP
    if(nb>=m) break;
    c0 =n0;  c1 =n1;  c2 =n2;  c3 =n3;  c4 =n4;  c5 =n5;  c6 =n6;  c7 =n7;
    c8 =n8;  c9 =n9;  c10=n10; c11=n11; c12=n12; c13=n13; c14=n14; c15=n15;
  }
#undef LD
  const int* list = lists + il*1024;
  for(int t=0;t<m;t+=64){
    int i=t+lane;
    unsigned long long word=__shfl(remv, (i<m? i:0)>>6);
    if(i<m && ((word>>(i&63))&1ull)) ssupp[img*KTOT+list[i]]=1;
  }
}

// ---------------- K4: compact survivors; LDS-staged predicate -----------------
__global__ __launch_bounds__(256) void k_out(const float* __restrict__ sbox,
    const float* __restrict__ sscore, const int* __restrict__ ssupp,
    float* __restrict__ out){
  const int img=blockIdx.x;
  const int tid=threadIdx.x;
  __shared__ unsigned char s_ok[KTOT];
  __shared__ unsigned short list[POST];
  __shared__ int s_c;
  for(int i=tid;i<KTOT;i+=256) s_ok[i]=(ssupp[img*KTOT+i]==0)?1:0;
  __syncthreads();
  if(tid<64){
    int base=0;
    for(int t=0;t<KTOT && base<POST;t+=64){
      int r=t+tid;
      bool pred=(r<KTOT) && s_ok[r];
      unsigned long long b=__ballot(pred);
      int pre=__popcll(b & ((1ull<<tid)-1ull));
      if(pred && base+pre<POST) list[base+pre]=(unsigned short)r;
      base+=__popcll(b);
    }
    if(tid==0) s_c=min(base,POST);
  }
  __syncthreads();
  const int c=s_c;
  for(int o=tid;o<POST;o+=256){
    float* row=out+((size_t)img*POST+o)*5;
    if(o<c){
      int r=list[o];
      const float* b=sbox+((size_t)img*KTOT+r)*4;
      row[0]=b[0]; row[1]=b[1]; row[2]=b[2]; row[3]=b[3];
      row[4]=sscore[img*KTOT+r];
    } else {
      row[0]=0.f; row[1]=0.f; row[2]=0.f; row[3]=0.f; row[4]=0.f;
    }
  }
}

extern "C" void kernel_launch(void* const* d_in, const int* in_sizes, int n_in,
                              void* d_out, int out_size, void* d_ws, size_t ws_size,
                              hipStream_t stream){
  const float* obj=(const float*)d_in[0];
  const float* del=(const float*)d_in[1];
  const float* anc=(const float*)d_in[2];
  float* out=(float*)d_out;

  char* w=(char*)d_ws;
  size_t off=0;
  auto alloc=[&](size_t bytes)->void*{
    void* p=w+off; off+=(bytes+255)&~(size_t)255; return p;
  };
  int*  sel    =(int*)  alloc(sizeof(int)*NIMG*KTOT);
  int*  sel2   =(int*)  alloc(sizeof(int)*NIMG*KTOT);
  float* pbox  =(float*)alloc(sizeof(float)*NIMG*KTOT*4);
  float* pscore=(float*)alloc(sizeof(float)*NIMG*KTOT);
  int*  plvl   =(int*)  alloc(sizeof(int)*NIMG*KTOT);
  unsigned long long* gkey=(unsigned long long*)alloc(sizeof(unsigned long long)*NIMG*KTOT);
  float* sbox  =(float*)alloc(sizeof(float)*NIMG*KTOT*4);
  float* sscore=(float*)alloc(sizeof(float)*NIMG*KTOT);
  int*  slvl   =(int*)  alloc(sizeof(int)*NIMG*KTOT);
  int*  ssupp  =(int*)  alloc(sizeof(int)*NIMG*KTOT);
  unsigned* gmaxu=(unsigned*)alloc(sizeof(unsigned)*NIMG);
  int*  eqbuf  =(int*)  alloc(sizeof(int)*40*2048);
  int*  lists  =(int*)  alloc(sizeof(int)*40*1024);
  int*  mcnt   =(int*)  alloc(sizeof(int)*40);
  float4* nbox =(float4*)alloc(sizeof(float4)*40*1024);
  float* narea =(float*)alloc(sizeof(float)*40*1024);
  unsigned long long* mask=(unsigned long long*)alloc(sizeof(unsigned long long)*40*1024*16);
  unsigned* ghist=(unsigned*)alloc(sizeof(unsigned)*40*2048);
  unsigned* gpref=(unsigned*)alloc(sizeof(unsigned)*40);
  int*  gkrem  =(int*)  alloc(sizeof(int)*40);
  int*  gcnt   =(int*)  alloc(sizeof(int)*80);
  int*  grank  =(int*)  alloc(sizeof(int)*NIMG*KTOT);

  hipLaunchKernelGGL(k_zero,    dim3((40*2048+NIMG*KTOT+NIMG+255)/256), dim3(256), 0, stream,
                     ghist, grank, gmaxu);
  hipLaunchKernelGGL(k_hist<0>, dim3(40,NSUB), dim3(256), 0, stream, obj, gpref, ghist);
  hipLaunchKernelGGL(k_scan<0>, dim3(40), dim3(256), 0, stream, ghist, gpref, gkrem, gcnt);
  hipLaunchKernelGGL(k_hist<1>, dim3(40,NSUB), dim3(256), 0, stream, obj, gpref, ghist);
  hipLaunchKernelGGL(k_scan<1>, dim3(40), dim3(256), 0, stream, ghist, gpref, gkrem, gcnt);
  hipLaunchKernelGGL(k_sel,    dim3(40,NSUB), dim3(256), 0, stream, obj, gpref, gkrem,
                     gcnt, sel, eqbuf);
  hipLaunchKernelGGL(k_sortd,  dim3(40,4), dim3(256), 0, stream, obj, gkrem, gcnt,
                     sel, sel2, eqbuf);
  hipLaunchKernelGGL(k_decode, dim3(NIMG*18), dim3(256), 0, stream, obj, del, anc, sel2,
                     pbox, pscore, plvl, gkey, gmaxu);
  hipLaunchKernelGGL(k_rankp,  dim3(NIMG,18,18), dim3(256), 0, stream, gkey, grank);
  hipLaunchKernelGGL(k_scatter,dim3(NIMG*18), dim3(256), 0, stream, grank,
                     (const float4*)pbox, pscore, plvl,
                     (float4*)sbox, sscore, slvl, ssupp);
  hipLaunchKernelGGL(k_list,   dim3(40), dim3(256), 0, stream, sbox, slvl, ssupp, gmaxu,
                     lists, mcnt, nbox, narea);
  hipLaunchKernelGGL(k_mask,   dim3(40,64), dim3(256), 0, stream, nbox, narea, mcnt, mask);
  hipLaunchKernelGGL(k_reduce, dim3(40), dim3(256), 0, stream, mask, mcnt, lists, ssupp);
  hipLaunchKernelGGL(k_out,    dim3(NIMG), dim3(256), 0, stream, sbox, sscore, ssupp, out);
}